// Round 1
// 317.657 us; speedup vs baseline: 1.0619x; 1.0619x over previous
//
#include <hip/hip_runtime.h>

#define NN 50000
#define NE 800000
#define NB ((NN + 255) / 256)   // 196 scan blocks
#define NBUCK ((NN + 255) / 256) // 196 dst-buckets of 256 nodes
#define EPB 4096                 // edges per k_bin block (16 per thread)

typedef unsigned int uint32;
typedef unsigned short ushort16;
typedef __attribute__((ext_vector_type(8))) short bf16x8;
typedef __attribute__((ext_vector_type(4))) float f32x4;

__device__ __forceinline__ ushort16 f2bf(float f) {
    uint32 u = __float_as_uint(f);
    u += 0x7fff + ((u >> 16) & 1);      // round-to-nearest-even
    return (ushort16)(u >> 16);
}
__device__ __forceinline__ float bf2f(ushort16 h) {
    return __uint_as_float(((uint32)h) << 16);
}
__device__ __forceinline__ float bf_lo(uint32 u) {
    return __uint_as_float(u << 16);
}
__device__ __forceinline__ float bf_hi(uint32 u) {
    return __uint_as_float(u & 0xffff0000u);
}
__device__ __forceinline__ bf16x8 pack8(const float4 a, const float4 b) {
    union { bf16x8 v; ushort16 u[8]; } r;
    r.u[0] = f2bf(a.x); r.u[1] = f2bf(a.y); r.u[2] = f2bf(a.z); r.u[3] = f2bf(a.w);
    r.u[4] = f2bf(b.x); r.u[5] = f2bf(b.y); r.u[6] = f2bf(b.z); r.u[7] = f2bf(b.w);
    return r.v;
}

// ---------------------------------------------------------------------------
// Weight pre-pack (once per launch): fp32 -> bf16 B-fragment order tables.
// ---------------------------------------------------------------------------
__global__ __launch_bounds__(256) void k_pack12(
    const float* __restrict__ w1, const float* __restrict__ w2,
    ushort16* __restrict__ pw)
{
    const int i = blockIdx.x * 256 + threadIdx.x;   // 0..16383
    const int j  = i & 7;
    const int ln = (i >> 3) & 63;
    const int s  = (i >> 9) & 3;
    const int cc = i >> 11;
    const int k  = s * 32 + ((ln >> 4) * 8) + j;    // 0..127
    const int n  = cc * 16 + (ln & 15);             // 0..127
    pw[i] = f2bf((n < 64) ? w1[k * 64 + n] : w2[k * 64 + (n - 64)]);
}

__global__ __launch_bounds__(256) void k_packp(
    const float* __restrict__ w, ushort16* __restrict__ pw)
{
    const int i = blockIdx.x * 256 + threadIdx.x;   // 0..16383
    const int j  = i & 7;
    const int ln = (i >> 3) & 63;
    const int s  = (i >> 9) & 7;
    const int cc = i >> 12;
    const int k  = s * 32 + ((ln >> 4) * 8) + j;    // zcat idx (k-dim)
    const int n  = cc * 16 + (ln & 15);             // output col
    pw[i] = f2bf(w[(k >> 2) * 256 + (k & 3) * 64 + n]);
}

__global__ __launch_bounds__(256) void k_packl3(
    const float* __restrict__ w, ushort16* __restrict__ pw)
{
    const int i = blockIdx.x * 256 + threadIdx.x;   // 0..4095
    const int j  = i & 7;
    const int ln = (i >> 3) & 63;
    const int s  = (i >> 9) & 1;
    const int cc = i >> 10;                         // 0..3
    const int k  = s * 32 + ((ln >> 4) * 8) + j;    // 0..63
    const int n  = cc * 16 + (ln & 15);             // 0..63
    pw[i] = f2bf(w[k * 64 + n]);
}

// ---------------------------------------------------------------------------
// k_lin12 (MFMA): [a | skip] = x @ [W1 | W2] + [b1 | b2]; a also emitted bf16.
// ---------------------------------------------------------------------------
__global__ __launch_bounds__(256) void k_lin12(
    const float* __restrict__ x, const ushort16* __restrict__ pw,
    const float* __restrict__ b1, const float* __restrict__ b2,
    float* __restrict__ a, ushort16* __restrict__ ab, float* __restrict__ skip)
{
    const int tid = threadIdx.x;
    const int lane = tid & 63;
    const int g = tid >> 6;
    const int m = lane & 15;
    const int quad = lane >> 4;
    const int rowBase = blockIdx.x * 64 + g * 16;

    const int arow = min(rowBase + m, NN - 1);
    const float* xr = x + (size_t)arow * 128 + quad * 8;

    f32x4 acc[8];
#pragma unroll
    for (int c = 0; c < 8; ++c)
#pragma unroll
        for (int r = 0; r < 4; ++r) acc[c][r] = 0.f;

#pragma unroll
    for (int s = 0; s < 4; ++s) {
        const float4 xa = *(const float4*)(xr + s * 32);
        const float4 xb = *(const float4*)(xr + s * 32 + 4);
        const bf16x8 af = pack8(xa, xb);
#pragma unroll
        for (int c = 0; c < 8; ++c) {
            const bf16x8 bf = *(const bf16x8*)&pw[((c * 4 + s) * 64 + lane) * 8];
            acc[c] = __builtin_amdgcn_mfma_f32_16x16x32_bf16(af, bf, acc[c], 0, 0, 0);
        }
    }

#pragma unroll
    for (int c = 0; c < 8; ++c) {
        const int colg = c * 16 + m;
        const float bv = (colg < 64) ? b1[colg] : b2[colg - 64];
#pragma unroll
        for (int reg = 0; reg < 4; ++reg) {
            const int gr = rowBase + quad * 4 + reg;
            if (gr < NN) {
                const float v = acc[c][reg] + bv;
                if (colg < 64) {
                    a[gr * 64 + colg]  = v;
                    ab[gr * 64 + colg] = f2bf(v);
                } else {
                    skip[gr * 64 + (colg - 64)] = v;
                }
            }
        }
    }
}

// ---------------------------------------------------------------------------
// k_t: t[n,h] = a[n,:] @ u[:,h]   ([NN,64]@[64,4]) — one thread per (n,h)
// ---------------------------------------------------------------------------
__global__ __launch_bounds__(256) void k_t(
    const float* __restrict__ a, const float* __restrict__ u,
    float* __restrict__ t)
{
    const int gid = blockIdx.x * 256 + threadIdx.x;
    if (gid >= NN * 4) return;
    const int n = gid >> 2, h = gid & 3;
    const float* ar = a + n * 64;
    float s = 0.f;
#pragma unroll 4
    for (int k = 0; k < 64; ++k) s += ar[k] * u[k * 4 + h];
    t[gid] = s;
}

// ---------------------------------------------------------------------------
// k_lin3m (MFMA): skip = h_bf16 @ W3 + b3  ([NN,64]@[64,64], K=64).
// ---------------------------------------------------------------------------
__global__ __launch_bounds__(256) void k_lin3m(
    const ushort16* __restrict__ hb, const ushort16* __restrict__ pw,
    const float* __restrict__ b, float* __restrict__ outp)
{
    const int tid = threadIdx.x;
    const int lane = tid & 63;
    const int g = tid >> 6;
    const int m = lane & 15;
    const int quad = lane >> 4;
    const int rowBase = blockIdx.x * 64 + g * 16;

    const int arow = min(rowBase + m, NN - 1);
    const ushort16* zrow = hb + (size_t)arow * 64 + quad * 8;

    f32x4 acc[4];
#pragma unroll
    for (int c = 0; c < 4; ++c)
#pragma unroll
        for (int r = 0; r < 4; ++r) acc[c][r] = 0.f;

#pragma unroll
    for (int s = 0; s < 2; ++s) {
        const bf16x8 af = *(const bf16x8*)(zrow + s * 32);
#pragma unroll
        for (int c = 0; c < 4; ++c) {
            const bf16x8 bf = *(const bf16x8*)&pw[((c * 2 + s) * 64 + lane) * 8];
            acc[c] = __builtin_amdgcn_mfma_f32_16x16x32_bf16(af, bf, acc[c], 0, 0, 0);
        }
    }

#pragma unroll
    for (int c = 0; c < 4; ++c) {
        const int colg = c * 16 + m;
        const float bv = b[colg];
#pragma unroll
        for (int reg = 0; reg < 4; ++reg) {
            const int gr = rowBase + quad * 4 + reg;
            if (gr < NN) outp[gr * 64 + colg] = acc[c][reg] + bv;
        }
    }
}

// ---------------------------------------------------------------------------
// CSR build: histogram -> hierarchical scan -> BUCKETED two-pass scatter.
// Bucket = 256 consecutive dst nodes (196 buckets). Bucket base offsets in
// the edge array are row_ptr at bucket boundaries (free from the scan).
// ---------------------------------------------------------------------------
__global__ __launch_bounds__(256) void k_hist(const int* __restrict__ ei,
                                              int* __restrict__ deg)
{
    const int i0 = (blockIdx.x * 256 + threadIdx.x) * 4;
    if (i0 + 3 < NE) {
        const int4 d4 = *(const int4*)&ei[NE + i0];
        atomicAdd(&deg[d4.x], 1);
        atomicAdd(&deg[d4.y], 1);
        atomicAdd(&deg[d4.z], 1);
        atomicAdd(&deg[d4.w], 1);
    } else {
        for (int i = i0; i < NE; ++i) atomicAdd(&deg[ei[NE + i]], 1);
    }
}

__global__ __launch_bounds__(256) void k_blocksum(const int* __restrict__ deg,
                                                  int* __restrict__ bsum)
{
    __shared__ int red[256];
    const int t = threadIdx.x;
    const int i = blockIdx.x * 256 + t;
    red[t] = (i < NN) ? deg[i] : 0;
    __syncthreads();
    for (int off = 128; off > 0; off >>= 1) {
        if (t < off) red[t] += red[t + off];
        __syncthreads();
    }
    if (t == 0) bsum[blockIdx.x] = red[0];
}

__global__ __launch_bounds__(256) void k_scanb(int* __restrict__ bsum)
{
    __shared__ int s[256];
    const int t = threadIdx.x;
    s[t] = (t < NB) ? bsum[t] : 0;
    __syncthreads();
    for (int off = 1; off < 256; off <<= 1) {
        const int v = (t >= off) ? s[t - off] : 0;
        __syncthreads();
        s[t] += v;
        __syncthreads();
    }
    if (t < NB) bsum[t] = (t == 0) ? 0 : s[t - 1];
}

__global__ __launch_bounds__(256) void k_scanfin(const int* __restrict__ deg,
                                                 const int* __restrict__ bsum,
                                                 int* __restrict__ row_ptr,
                                                 int* __restrict__ bcnt)
{
    __shared__ int s[256];
    const int t = threadIdx.x;
    const int i = blockIdx.x * 256 + t;
    const int v = (i < NN) ? deg[i] : 0;
    s[t] = v;
    __syncthreads();
    for (int off = 1; off < 256; off <<= 1) {
        const int u = (t >= off) ? s[t - off] : 0;
        __syncthreads();
        s[t] += u;
        __syncthreads();
    }
    const int excl = s[t] - v + bsum[blockIdx.x];
    if (i < NN) {
        row_ptr[i] = excl;
        if ((i & 255) == 0) bcnt[i >> 8] = excl;   // bucket append cursor init
    }
    if (i == NN - 1) row_ptr[NN] = excl + v;
}

// Pass A: bin edges into bucket-major `pairs` (packed src | dloc<<16).
// Block-local LDS histogram -> one global atomic per (block,bucket) reserves
// a contiguous chunk -> chunk writes mostly fill whole 64B lines.
__global__ __launch_bounds__(256) void k_bin(const int* __restrict__ ei,
                                             int* __restrict__ bcnt,
                                             uint32* __restrict__ pairs)
{
    __shared__ int hist[NBUCK];
    __shared__ int gbase[NBUCK];
    const int t = threadIdx.x;
    const int base = blockIdx.x * EPB;

    for (int b = t; b < NBUCK; b += 256) hist[b] = 0;
    __syncthreads();

    uint32 pk[16];
    int bk[16], rk[16];
#pragma unroll
    for (int k = 0; k < 16; ++k) {
        const int e = base + k * 256 + t;
        if (e < NE) {
            const int s = ei[e];
            const int d = ei[NE + e];
            bk[k] = d >> 8;
            pk[k] = (uint32)s | ((uint32)(d & 255) << 16);
            rk[k] = atomicAdd(&hist[bk[k]], 1);
        }
    }
    __syncthreads();

    for (int b = t; b < NBUCK; b += 256)
        gbase[b] = hist[b] ? atomicAdd(&bcnt[b], hist[b]) : 0;
    __syncthreads();

#pragma unroll
    for (int k = 0; k < 16; ++k) {
        const int e = base + k * 256 + t;
        if (e < NE) pairs[gbase[bk[k]] + rk[k]] = pk[k];
    }
}

// Pass B: one workgroup per bucket. Per-node cursors live in LDS; scatter
// stays inside a ~16KB ssrc window -> lines fully filled in this XCD's L2.
__global__ __launch_bounds__(256) void k_binscat(const int* __restrict__ row_ptr,
                                                 const uint32* __restrict__ pairs,
                                                 int* __restrict__ ssrc)
{
    __shared__ int lptr[257];
    __shared__ int lcur[256];
    const int b = blockIdx.x;
    const int n0 = b << 8;
    const int t = threadIdx.x;

    lptr[t] = row_ptr[min(n0 + t, NN)];
    if (t == 0) lptr[256] = row_ptr[min(n0 + 256, NN)];
    lcur[t] = 0;
    __syncthreads();

    const int e0 = lptr[0], e1 = lptr[256];
    for (int e = e0 + t; e < e1; e += 256) {
        const uint32 p = pairs[e];
        const int dloc = p >> 16;
        const int r = atomicAdd(&lcur[dloc], 1);
        ssrc[lptr[dloc] + r] = (int)(p & 0xffffu);
    }
}

// ---------------------------------------------------------------------------
// k_agg: one wave per dst node; TWO edges per iteration (lane halves).
// ---------------------------------------------------------------------------
__global__ __launch_bounds__(256) void k_agg(
    const int* __restrict__ row_ptr, const int* __restrict__ ssrc,
    const float* __restrict__ t, const uint32* __restrict__ abu,
    const float* __restrict__ c, uint4* __restrict__ zcat4)
{
    const int lane = threadIdx.x & 63;
    const int node = (blockIdx.x * 256 + threadIdx.x) >> 6;
    if (node >= NN) return;

    const int half = lane >> 5;
    const int u = lane & 31;

    const int r0 = row_ptr[node];
    const int r1 = row_ptr[node + 1];
    const int deg = r1 - r0;
    const float invdeg = (deg > 0) ? 1.f / (float)deg : 0.f;

    const float4 tc = *(const float4*)c;
    const float4 td = ((const float4*)t)[node];

    float z00 = 0.f, z01 = 0.f, z10 = 0.f, z11 = 0.f;
    float z20 = 0.f, z21 = 0.f, z30 = 0.f, z31 = 0.f;

    for (int base = r0; base < r1; base += 64) {
        const int m = min(64, r1 - base);

        int src = 0;
        float q0 = 0.f, q1 = 0.f, q2 = 0.f, q3 = 0.f;
        if (lane < m) {
            src = ssrc[base + lane];
            const float4 ts = ((const float4*)t)[src];
            const float l0 = ts.x - td.x + tc.x;
            const float l1 = ts.y - td.y + tc.y;
            const float l2 = ts.z - td.z + tc.z;
            const float l3 = ts.w - td.w + tc.w;
            const float mx = fmaxf(fmaxf(l0, l1), fmaxf(l2, l3));
            const float e0 = __expf(l0 - mx);
            const float e1 = __expf(l1 - mx);
            const float e2 = __expf(l2 - mx);
            const float e3 = __expf(l3 - mx);
            const float s = invdeg / (e0 + e1 + e2 + e3);
            q0 = e0 * s; q1 = e1 * s; q2 = e2 * s; q3 = e3 * s;
        }

        int e = 0;
        for (; e + 7 < m; e += 8) {
#pragma unroll
            for (int k = 0; k < 8; k += 2) {
                const int idx = e + k + half;
                const int se = __shfl(src, idx, 64);
                const float a0 = __shfl(q0, idx, 64);
                const float a1 = __shfl(q1, idx, 64);
                const float a2 = __shfl(q2, idx, 64);
                const float a3 = __shfl(q3, idx, 64);
                const uint32 av = abu[se * 32 + u];
                const float v0 = bf_lo(av), v1 = bf_hi(av);
                z00 += a0 * v0; z01 += a0 * v1;
                z10 += a1 * v0; z11 += a1 * v1;
                z20 += a2 * v0; z21 += a2 * v1;
                z30 += a3 * v0; z31 += a3 * v1;
            }
        }
        for (; e + 1 < m; e += 2) {
            const int idx = e + half;
            const int se = __shfl(src, idx, 64);
            const float a0 = __shfl(q0, idx, 64);
            const float a1 = __shfl(q1, idx, 64);
            const float a2 = __shfl(q2, idx, 64);
            const float a3 = __shfl(q3, idx, 64);
            const uint32 av = abu[se * 32 + u];
            const float v0 = bf_lo(av), v1 = bf_hi(av);
            z00 += a0 * v0; z01 += a0 * v1;
            z10 += a1 * v0; z11 += a1 * v1;
            z20 += a2 * v0; z21 += a2 * v1;
            z30 += a3 * v0; z31 += a3 * v1;
        }
        if (e < m) {
            const int se = __shfl(src, e, 64);
            const float a0 = __shfl(q0, e, 64);
            const float a1 = __shfl(q1, e, 64);
            const float a2 = __shfl(q2, e, 64);
            const float a3 = __shfl(q3, e, 64);
            if (half == 0) {
                const uint32 av = abu[se * 32 + u];
                const float v0 = bf_lo(av), v1 = bf_hi(av);
                z00 += a0 * v0; z01 += a0 * v1;
                z10 += a1 * v0; z11 += a1 * v1;
                z20 += a2 * v0; z21 += a2 * v1;
                z30 += a3 * v0; z31 += a3 * v1;
            }
        }
    }

    z00 += __shfl_xor(z00, 32, 64); z01 += __shfl_xor(z01, 32, 64);
    z10 += __shfl_xor(z10, 32, 64); z11 += __shfl_xor(z11, 32, 64);
    z20 += __shfl_xor(z20, 32, 64); z21 += __shfl_xor(z21, 32, 64);
    z30 += __shfl_xor(z30, 32, 64); z31 += __shfl_xor(z31, 32, 64);

    if (half == 0) {
        uint4 pk;
        pk.x = (uint32)f2bf(z00) | ((uint32)f2bf(z10) << 16);
        pk.y = (uint32)f2bf(z20) | ((uint32)f2bf(z30) << 16);
        pk.z = (uint32)f2bf(z01) | ((uint32)f2bf(z11) << 16);
        pk.w = (uint32)f2bf(z21) | ((uint32)f2bf(z31) << 16);
        zcat4[node * 32 + u] = pk;
    }
}

// ---------------------------------------------------------------------------
// k_post (MFMA): out = relu(zcat @ Wp + bias + skip) + bf16 copy.
// ---------------------------------------------------------------------------
__global__ __launch_bounds__(256) void k_post(
    const ushort16* __restrict__ zcat, const ushort16* __restrict__ pw,
    const float* __restrict__ bias, const float* __restrict__ skip,
    float* __restrict__ out, ushort16* __restrict__ outb)
{
    const int tid = threadIdx.x;
    const int lane = tid & 63;
    const int g = tid >> 6;
    const int m = lane & 15;
    const int quad = lane >> 4;
    const int rowBase = blockIdx.x * 64 + g * 16;

    const int arow = min(rowBase + m, NN - 1);
    const ushort16* zrow = zcat + (size_t)arow * 256 + quad * 8;

    f32x4 acc[4];
#pragma unroll
    for (int c = 0; c < 4; ++c)
#pragma unroll
        for (int r = 0; r < 4; ++r) acc[c][r] = 0.f;

#pragma unroll
    for (int s = 0; s < 8; ++s) {
        const bf16x8 af = *(const bf16x8*)(zrow + s * 32);
#pragma unroll
        for (int c = 0; c < 4; ++c) {
            const bf16x8 bf = *(const bf16x8*)&pw[((c * 8 + s) * 64 + lane) * 8];
            acc[c] = __builtin_amdgcn_mfma_f32_16x16x32_bf16(af, bf, acc[c], 0, 0, 0);
        }
    }

#pragma unroll
    for (int c = 0; c < 4; ++c) {
        const int colg = c * 16 + m;
        const float bv = bias[colg];
#pragma unroll
        for (int reg = 0; reg < 4; ++reg) {
            const int gr = rowBase + quad * 4 + reg;
            if (gr < NN) {
                const float v = fmaxf(acc[c][reg] + bv + skip[gr * 64 + colg], 0.f);
                out[gr * 64 + colg]  = v;
                outb[gr * 64 + colg] = f2bf(v);
            }
        }
    }
}

extern "C" void kernel_launch(void* const* d_in, const int* in_sizes, int n_in,
                              void* d_out, int out_size, void* d_ws, size_t ws_size,
                              hipStream_t stream) {
    const float* x       = (const float*)d_in[0];
    const int*   ei      = (const int*)d_in[1];   // [2, NE] int32
    const float* lin1_w  = (const float*)d_in[2];
    const float* lin1_b  = (const float*)d_in[3];
    const float* lin2_w  = (const float*)d_in[4];
    const float* lin2_b  = (const float*)d_in[5];
    const float* lin3_w  = (const float*)d_in[6];
    const float* lin3_b  = (const float*)d_in[7];
    const float* conv1_w = (const float*)d_in[8];
    const float* conv1_u = (const float*)d_in[9];
    const float* conv1_c = (const float*)d_in[10];
    const float* conv1_bias = (const float*)d_in[11];
    const float* conv2_w = (const float*)d_in[12];
    const float* conv2_u = (const float*)d_in[13];
    const float* conv2_c = (const float*)d_in[14];
    const float* conv2_bias = (const float*)d_in[15];
    float* out = (float*)d_out;

    // workspace layout (~65 MB, 16B-aligned sections)
    char* p = (char*)d_ws;
    float* a      = (float*)p;           p += (size_t)NN * 64 * 4;   // fp32 a / h
    float* skip   = (float*)p;           p += (size_t)NN * 64 * 4;
    float* tt     = (float*)p;           p += (size_t)NN * 4 * 4;
    ushort16* ab  = (ushort16*)p;        p += (size_t)NN * 64 * 2;   // bf16 a / h
    ushort16* zc  = (ushort16*)p;        p += (size_t)NN * 256 * 2;  // bf16 z
    ushort16* pw12 = (ushort16*)p;       p += 16384 * 2;             // packed [W1|W2]
    ushort16* pwc1 = (ushort16*)p;       p += 16384 * 2;             // packed conv1_w
    ushort16* pwc2 = (ushort16*)p;       p += 16384 * 2;             // packed conv2_w
    ushort16* pwl3 = (ushort16*)p;       p += 4096 * 2;              // packed lin3_w
    int* ssrc     = (int*)p;             p += (size_t)NE * 4;
    int* deg      = (int*)p;             p += (size_t)NN * 4;
    int* row_ptr  = (int*)p;             p += (size_t)(NN + 1) * 4;
    int* bcnt     = (int*)p;             p += 256 * 4;               // bucket cursors
    int* bsum     = (int*)p;             p += 256 * 4;
    uint32* pairs = (uint32*)p;          p += (size_t)NE * 4;        // binned edges

    // ---- weight pre-pack (tiny) + CSR build ----
    k_pack12<<<64, 256, 0, stream>>>(lin1_w, lin2_w, pw12);
    k_packp<<<64, 256, 0, stream>>>(conv1_w, pwc1);
    k_packp<<<64, 256, 0, stream>>>(conv2_w, pwc2);
    k_packl3<<<16, 256, 0, stream>>>(lin3_w, pwl3);
    hipMemsetAsync(deg, 0, (size_t)NN * sizeof(int), stream);
    k_hist<<<(NE / 4 + 255) / 256, 256, 0, stream>>>(ei, deg);
    k_blocksum<<<NB, 256, 0, stream>>>(deg, bsum);
    k_scanb<<<1, 256, 0, stream>>>(bsum);
    k_scanfin<<<NB, 256, 0, stream>>>(deg, bsum, row_ptr, bcnt);
    k_bin<<<(NE + EPB - 1) / EPB, 256, 0, stream>>>(ei, bcnt, pairs);
    k_binscat<<<NBUCK, 256, 0, stream>>>(row_ptr, pairs, ssrc);

    // ---- layer 1 ----
    k_lin12<<<(NN + 63) / 64, 256, 0, stream>>>(x, pw12, lin1_b, lin2_b, a, ab, skip);
    k_t<<<(NN * 4 + 255) / 256, 256, 0, stream>>>(a, conv1_u, tt);
    k_agg<<<(NN + 3) / 4, 256, 0, stream>>>(row_ptr, ssrc, tt, (const uint32*)ab,
                                            conv1_c, (uint4*)zc);
    k_post<<<(NN + 63) / 64, 256, 0, stream>>>(zc, pwc1, conv1_bias, skip, a, ab);

    // ---- layer 2 ---- (h fp32 in a, bf16 in ab)
    k_t<<<(NN * 4 + 255) / 256, 256, 0, stream>>>(a, conv2_u, tt);
    k_lin3m<<<(NN + 63) / 64, 256, 0, stream>>>(ab, pwl3, lin3_b, skip);
    k_agg<<<(NN + 3) / 4, 256, 0, stream>>>(row_ptr, ssrc, tt, (const uint32*)ab,
                                            conv2_c, (uint4*)zc);
    k_post<<<(NN + 63) / 64, 256, 0, stream>>>(zc, pwc2, conv2_bias, skip, out, ab);
}

// Round 2
// 270.433 us; speedup vs baseline: 1.2473x; 1.1746x over previous
//
#include <hip/hip_runtime.h>

#define NN 50000
#define NE 800000
#define NBUCK ((NN + 255) / 256) // 196 dst-buckets of 256 nodes
#define EPB 4096                 // edges per k_bin block (16 per thread)
#define BCAP 8192                // padded per-bucket capacity (mean 4082, max~4.4k)

typedef unsigned int uint32;
typedef unsigned short ushort16;
typedef __attribute__((ext_vector_type(8))) short bf16x8;
typedef __attribute__((ext_vector_type(4))) float f32x4;

__device__ __forceinline__ ushort16 f2bf(float f) {
    uint32 u = __float_as_uint(f);
    u += 0x7fff + ((u >> 16) & 1);      // round-to-nearest-even
    return (ushort16)(u >> 16);
}
__device__ __forceinline__ float bf_lo(uint32 u) {
    return __uint_as_float(u << 16);
}
__device__ __forceinline__ float bf_hi(uint32 u) {
    return __uint_as_float(u & 0xffff0000u);
}
__device__ __forceinline__ bf16x8 pack8(const float4 a, const float4 b) {
    union { bf16x8 v; ushort16 u[8]; } r;
    r.u[0] = f2bf(a.x); r.u[1] = f2bf(a.y); r.u[2] = f2bf(a.z); r.u[3] = f2bf(a.w);
    r.u[4] = f2bf(b.x); r.u[5] = f2bf(b.y); r.u[6] = f2bf(b.z); r.u[7] = f2bf(b.w);
    return r.v;
}

// ---------------------------------------------------------------------------
// k_packall: all weight pre-packs fused (fp32 -> bf16 B-fragment order) and
// bcnt zero-init. Work items: 16384 (pw12) + 16384 (pwc1) + 16384 (pwc2)
// + 4096 (pwl3) + 256 (bcnt) = 53504 -> 209 blocks.
// ---------------------------------------------------------------------------
__device__ __forceinline__ ushort16 packp_val(const float* __restrict__ w, int i) {
    const int j  = i & 7;
    const int ln = (i >> 3) & 63;
    const int s  = (i >> 9) & 7;
    const int cc = i >> 12;
    const int k  = s * 32 + ((ln >> 4) * 8) + j;    // zcat idx (k-dim)
    const int n  = cc * 16 + (ln & 15);             // output col
    return f2bf(w[(k >> 2) * 256 + (k & 3) * 64 + n]);
}

__global__ __launch_bounds__(256) void k_packall(
    const float* __restrict__ w1, const float* __restrict__ w2,
    const float* __restrict__ wc1, const float* __restrict__ wc2,
    const float* __restrict__ wl3,
    ushort16* __restrict__ pw12, ushort16* __restrict__ pwc1,
    ushort16* __restrict__ pwc2, ushort16* __restrict__ pwl3,
    int* __restrict__ bcnt)
{
    const int gid = blockIdx.x * 256 + threadIdx.x;
    if (gid < 16384) {
        const int i = gid;
        const int j  = i & 7;
        const int ln = (i >> 3) & 63;
        const int s  = (i >> 9) & 3;
        const int cc = i >> 11;
        const int k  = s * 32 + ((ln >> 4) * 8) + j;    // 0..127
        const int n  = cc * 16 + (ln & 15);             // 0..127
        pw12[i] = f2bf((n < 64) ? w1[k * 64 + n] : w2[k * 64 + (n - 64)]);
    } else if (gid < 32768) {
        pwc1[gid - 16384] = packp_val(wc1, gid - 16384);
    } else if (gid < 49152) {
        pwc2[gid - 32768] = packp_val(wc2, gid - 32768);
    } else if (gid < 53248) {
        const int i = gid - 49152;                      // 0..4095
        const int j  = i & 7;
        const int ln = (i >> 3) & 63;
        const int s  = (i >> 9) & 1;
        const int cc = i >> 10;                         // 0..3
        const int k  = s * 32 + ((ln >> 4) * 8) + j;    // 0..63
        const int n  = cc * 16 + (ln & 15);             // 0..63
        pwl3[i] = f2bf(wl3[k * 64 + n]);
    } else if (gid < 53504) {
        bcnt[gid - 53248] = 0;
    }
}

// ---------------------------------------------------------------------------
// k_lin12 (MFMA): [a | skip] = x @ [W1 | W2] + [b1 | b2]; a also emitted bf16.
// ---------------------------------------------------------------------------
__global__ __launch_bounds__(256) void k_lin12(
    const float* __restrict__ x, const ushort16* __restrict__ pw,
    const float* __restrict__ b1, const float* __restrict__ b2,
    float* __restrict__ a, ushort16* __restrict__ ab, float* __restrict__ skip)
{
    const int tid = threadIdx.x;
    const int lane = tid & 63;
    const int g = tid >> 6;
    const int m = lane & 15;
    const int quad = lane >> 4;
    const int rowBase = blockIdx.x * 64 + g * 16;

    const int arow = min(rowBase + m, NN - 1);
    const float* xr = x + (size_t)arow * 128 + quad * 8;

    f32x4 acc[8];
#pragma unroll
    for (int c = 0; c < 8; ++c)
#pragma unroll
        for (int r = 0; r < 4; ++r) acc[c][r] = 0.f;

#pragma unroll
    for (int s = 0; s < 4; ++s) {
        const float4 xa = *(const float4*)(xr + s * 32);
        const float4 xb = *(const float4*)(xr + s * 32 + 4);
        const bf16x8 af = pack8(xa, xb);
#pragma unroll
        for (int c = 0; c < 8; ++c) {
            const bf16x8 bf = *(const bf16x8*)&pw[((c * 4 + s) * 64 + lane) * 8];
            acc[c] = __builtin_amdgcn_mfma_f32_16x16x32_bf16(af, bf, acc[c], 0, 0, 0);
        }
    }

#pragma unroll
    for (int c = 0; c < 8; ++c) {
        const int colg = c * 16 + m;
        const float bv = (colg < 64) ? b1[colg] : b2[colg - 64];
#pragma unroll
        for (int reg = 0; reg < 4; ++reg) {
            const int gr = rowBase + quad * 4 + reg;
            if (gr < NN) {
                const float v = acc[c][reg] + bv;
                if (colg < 64) {
                    a[gr * 64 + colg]  = v;
                    ab[gr * 64 + colg] = f2bf(v);
                } else {
                    skip[gr * 64 + (colg - 64)] = v;
                }
            }
        }
    }
}

// ---------------------------------------------------------------------------
// k_t: t[n,h] = a[n,:] @ u[:,h]   ([NN,64]@[64,4]) — one thread per (n,h)
// ---------------------------------------------------------------------------
__global__ __launch_bounds__(256) void k_t(
    const float* __restrict__ a, const float* __restrict__ u,
    float* __restrict__ t)
{
    const int gid = blockIdx.x * 256 + threadIdx.x;
    if (gid >= NN * 4) return;
    const int n = gid >> 2, h = gid & 3;
    const float* ar = a + n * 64;
    float s = 0.f;
#pragma unroll 4
    for (int k = 0; k < 64; ++k) s += ar[k] * u[k * 4 + h];
    t[gid] = s;
}

// ---------------------------------------------------------------------------
// k_lin3m (MFMA): skip = h_bf16 @ W3 + b3  ([NN,64]@[64,64], K=64).
// ---------------------------------------------------------------------------
__global__ __launch_bounds__(256) void k_lin3m(
    const ushort16* __restrict__ hb, const ushort16* __restrict__ pw,
    const float* __restrict__ b, float* __restrict__ outp)
{
    const int tid = threadIdx.x;
    const int lane = tid & 63;
    const int g = tid >> 6;
    const int m = lane & 15;
    const int quad = lane >> 4;
    const int rowBase = blockIdx.x * 64 + g * 16;

    const int arow = min(rowBase + m, NN - 1);
    const ushort16* zrow = hb + (size_t)arow * 64 + quad * 8;

    f32x4 acc[4];
#pragma unroll
    for (int c = 0; c < 4; ++c)
#pragma unroll
        for (int r = 0; r < 4; ++r) acc[c][r] = 0.f;

#pragma unroll
    for (int s = 0; s < 2; ++s) {
        const bf16x8 af = *(const bf16x8*)(zrow + s * 32);
#pragma unroll
        for (int c = 0; c < 4; ++c) {
            const bf16x8 bf = *(const bf16x8*)&pw[((c * 2 + s) * 64 + lane) * 8];
            acc[c] = __builtin_amdgcn_mfma_f32_16x16x32_bf16(af, bf, acc[c], 0, 0, 0);
        }
    }

#pragma unroll
    for (int c = 0; c < 4; ++c) {
        const int colg = c * 16 + m;
        const float bv = b[colg];
#pragma unroll
        for (int reg = 0; reg < 4; ++reg) {
            const int gr = rowBase + quad * 4 + reg;
            if (gr < NN) outp[gr * 64 + colg] = acc[c][reg] + bv;
        }
    }
}

// ---------------------------------------------------------------------------
// CSR build, histogram-free: k_bin appends edges into bucket-PADDED `pairs`
// (capacity BCAP/bucket, cursor bcnt[b] from 0). k_bucketscan scans the 196
// bucket totals into global edge-bases. k_binscat recovers per-node degrees
// with an LDS histogram + LDS scan, emits row_ptr, and scatters ssrc within
// its bucket's ~16KB L2-resident window.
// ---------------------------------------------------------------------------
__global__ __launch_bounds__(256) void k_bin(const int* __restrict__ ei,
                                             int* __restrict__ bcnt,
                                             uint32* __restrict__ pairs)
{
    __shared__ int hist[NBUCK];
    __shared__ int gbase[NBUCK];
    const int t = threadIdx.x;
    const int base = blockIdx.x * EPB;

    for (int b = t; b < NBUCK; b += 256) hist[b] = 0;
    __syncthreads();

    uint32 pk[16];
    int bk[16], rk[16];
#pragma unroll
    for (int k = 0; k < 16; ++k) {
        const int e = base + k * 256 + t;
        if (e < NE) {
            const int s = ei[e];
            const int d = ei[NE + e];
            bk[k] = d >> 8;
            pk[k] = (uint32)s | ((uint32)(d & 255) << 16);
            rk[k] = atomicAdd(&hist[bk[k]], 1);
        }
    }
    __syncthreads();

    for (int b = t; b < NBUCK; b += 256)
        gbase[b] = hist[b] ? atomicAdd(&bcnt[b], hist[b]) : 0;
    __syncthreads();

#pragma unroll
    for (int k = 0; k < 16; ++k) {
        const int e = base + k * 256 + t;
        if (e < NE) pairs[(size_t)bk[k] * BCAP + gbase[bk[k]] + rk[k]] = pk[k];
    }
}

__global__ __launch_bounds__(256) void k_bucketscan(const int* __restrict__ bcnt,
                                                    int* __restrict__ bbase,
                                                    int* __restrict__ row_ptr)
{
    __shared__ int s[256];
    const int t = threadIdx.x;
    const int v = (t < NBUCK) ? bcnt[t] : 0;
    s[t] = v;
    __syncthreads();
    for (int off = 1; off < 256; off <<= 1) {
        const int u = (t >= off) ? s[t - off] : 0;
        __syncthreads();
        s[t] += u;
        __syncthreads();
    }
    if (t < NBUCK) bbase[t] = s[t] - v;   // exclusive
    if (t == 0) row_ptr[NN] = NE;
}

__global__ __launch_bounds__(256) void k_binscat(const uint32* __restrict__ pairs,
                                                 const int* __restrict__ bcnt,
                                                 const int* __restrict__ bbase,
                                                 int* __restrict__ row_ptr,
                                                 int* __restrict__ ssrc)
{
    __shared__ int hist[256];
    __shared__ int s[256];
    __shared__ int lptr[256];
    __shared__ int lcur[256];
    const int b = blockIdx.x;
    const int t = threadIdx.x;
    const int total = bcnt[b];
    const int base = bbase[b];
    const uint32* pb = pairs + (size_t)b * BCAP;

    hist[t] = 0;
    __syncthreads();
    for (int e = t; e < total; e += 256) atomicAdd(&hist[pb[e] >> 16], 1);
    __syncthreads();

    const int v = hist[t];
    s[t] = v;
    __syncthreads();
    for (int off = 1; off < 256; off <<= 1) {
        const int u = (t >= off) ? s[t - off] : 0;
        __syncthreads();
        s[t] += u;
        __syncthreads();
    }
    const int excl = base + s[t] - v;
    lptr[t] = excl;
    lcur[t] = 0;
    const int n = (b << 8) + t;
    if (n < NN) row_ptr[n] = excl;
    __syncthreads();

    for (int e = t; e < total; e += 256) {
        const uint32 p = pb[e];
        const int d = p >> 16;
        const int r = atomicAdd(&lcur[d], 1);
        ssrc[lptr[d] + r] = (int)(p & 0xffffu);
    }
}

// ---------------------------------------------------------------------------
// k_agg: one wave per dst node; TWO edges per iteration (lane halves).
// ---------------------------------------------------------------------------
__global__ __launch_bounds__(256) void k_agg(
    const int* __restrict__ row_ptr, const int* __restrict__ ssrc,
    const float* __restrict__ t, const uint32* __restrict__ abu,
    const float* __restrict__ c, uint4* __restrict__ zcat4)
{
    const int lane = threadIdx.x & 63;
    const int node = (blockIdx.x * 256 + threadIdx.x) >> 6;
    if (node >= NN) return;

    const int half = lane >> 5;
    const int u = lane & 31;

    const int r0 = row_ptr[node];
    const int r1 = row_ptr[node + 1];
    const int deg = r1 - r0;
    const float invdeg = (deg > 0) ? 1.f / (float)deg : 0.f;

    const float4 tc = *(const float4*)c;
    const float4 td = ((const float4*)t)[node];

    float z00 = 0.f, z01 = 0.f, z10 = 0.f, z11 = 0.f;
    float z20 = 0.f, z21 = 0.f, z30 = 0.f, z31 = 0.f;

    for (int base = r0; base < r1; base += 64) {
        const int m = min(64, r1 - base);

        int src = 0;
        float q0 = 0.f, q1 = 0.f, q2 = 0.f, q3 = 0.f;
        if (lane < m) {
            src = ssrc[base + lane];
            const float4 ts = ((const float4*)t)[src];
            const float l0 = ts.x - td.x + tc.x;
            const float l1 = ts.y - td.y + tc.y;
            const float l2 = ts.z - td.z + tc.z;
            const float l3 = ts.w - td.w + tc.w;
            const float mx = fmaxf(fmaxf(l0, l1), fmaxf(l2, l3));
            const float e0 = __expf(l0 - mx);
            const float e1 = __expf(l1 - mx);
            const float e2 = __expf(l2 - mx);
            const float e3 = __expf(l3 - mx);
            const float s = invdeg / (e0 + e1 + e2 + e3);
            q0 = e0 * s; q1 = e1 * s; q2 = e2 * s; q3 = e3 * s;
        }

        int e = 0;
        for (; e + 7 < m; e += 8) {
#pragma unroll
            for (int k = 0; k < 8; k += 2) {
                const int idx = e + k + half;
                const int se = __shfl(src, idx, 64);
                const float a0 = __shfl(q0, idx, 64);
                const float a1 = __shfl(q1, idx, 64);
                const float a2 = __shfl(q2, idx, 64);
                const float a3 = __shfl(q3, idx, 64);
                const uint32 av = abu[se * 32 + u];
                const float v0 = bf_lo(av), v1 = bf_hi(av);
                z00 += a0 * v0; z01 += a0 * v1;
                z10 += a1 * v0; z11 += a1 * v1;
                z20 += a2 * v0; z21 += a2 * v1;
                z30 += a3 * v0; z31 += a3 * v1;
            }
        }
        for (; e + 1 < m; e += 2) {
            const int idx = e + half;
            const int se = __shfl(src, idx, 64);
            const float a0 = __shfl(q0, idx, 64);
            const float a1 = __shfl(q1, idx, 64);
            const float a2 = __shfl(q2, idx, 64);
            const float a3 = __shfl(q3, idx, 64);
            const uint32 av = abu[se * 32 + u];
            const float v0 = bf_lo(av), v1 = bf_hi(av);
            z00 += a0 * v0; z01 += a0 * v1;
            z10 += a1 * v0; z11 += a1 * v1;
            z20 += a2 * v0; z21 += a2 * v1;
            z30 += a3 * v0; z31 += a3 * v1;
        }
        if (e < m) {
            const int se = __shfl(src, e, 64);
            const float a0 = __shfl(q0, e, 64);
            const float a1 = __shfl(q1, e, 64);
            const float a2 = __shfl(q2, e, 64);
            const float a3 = __shfl(q3, e, 64);
            if (half == 0) {
                const uint32 av = abu[se * 32 + u];
                const float v0 = bf_lo(av), v1 = bf_hi(av);
                z00 += a0 * v0; z01 += a0 * v1;
                z10 += a1 * v0; z11 += a1 * v1;
                z20 += a2 * v0; z21 += a2 * v1;
                z30 += a3 * v0; z31 += a3 * v1;
            }
        }
    }

    z00 += __shfl_xor(z00, 32, 64); z01 += __shfl_xor(z01, 32, 64);
    z10 += __shfl_xor(z10, 32, 64); z11 += __shfl_xor(z11, 32, 64);
    z20 += __shfl_xor(z20, 32, 64); z21 += __shfl_xor(z21, 32, 64);
    z30 += __shfl_xor(z30, 32, 64); z31 += __shfl_xor(z31, 32, 64);

    if (half == 0) {
        uint4 pk;
        pk.x = (uint32)f2bf(z00) | ((uint32)f2bf(z10) << 16);
        pk.y = (uint32)f2bf(z20) | ((uint32)f2bf(z30) << 16);
        pk.z = (uint32)f2bf(z01) | ((uint32)f2bf(z11) << 16);
        pk.w = (uint32)f2bf(z21) | ((uint32)f2bf(z31) << 16);
        zcat4[node * 32 + u] = pk;
    }
}

// ---------------------------------------------------------------------------
// k_post (MFMA): out = relu(zcat @ Wp + bias + skip) + bf16 copy.
// ---------------------------------------------------------------------------
__global__ __launch_bounds__(256) void k_post(
    const ushort16* __restrict__ zcat, const ushort16* __restrict__ pw,
    const float* __restrict__ bias, const float* __restrict__ skip,
    float* __restrict__ out, ushort16* __restrict__ outb)
{
    const int tid = threadIdx.x;
    const int lane = tid & 63;
    const int g = tid >> 6;
    const int m = lane & 15;
    const int quad = lane >> 4;
    const int rowBase = blockIdx.x * 64 + g * 16;

    const int arow = min(rowBase + m, NN - 1);
    const ushort16* zrow = zcat + (size_t)arow * 256 + quad * 8;

    f32x4 acc[4];
#pragma unroll
    for (int c = 0; c < 4; ++c)
#pragma unroll
        for (int r = 0; r < 4; ++r) acc[c][r] = 0.f;

#pragma unroll
    for (int s = 0; s < 8; ++s) {
        const bf16x8 af = *(const bf16x8*)(zrow + s * 32);
#pragma unroll
        for (int c = 0; c < 4; ++c) {
            const bf16x8 bf = *(const bf16x8*)&pw[((c * 8 + s) * 64 + lane) * 8];
            acc[c] = __builtin_amdgcn_mfma_f32_16x16x32_bf16(af, bf, acc[c], 0, 0, 0);
        }
    }

#pragma unroll
    for (int c = 0; c < 4; ++c) {
        const int colg = c * 16 + m;
        const float bv = bias[colg];
#pragma unroll
        for (int reg = 0; reg < 4; ++reg) {
            const int gr = rowBase + quad * 4 + reg;
            if (gr < NN) {
                const float v = fmaxf(acc[c][reg] + bv + skip[gr * 64 + colg], 0.f);
                out[gr * 64 + colg]  = v;
                outb[gr * 64 + colg] = f2bf(v);
            }
        }
    }
}

extern "C" void kernel_launch(void* const* d_in, const int* in_sizes, int n_in,
                              void* d_out, int out_size, void* d_ws, size_t ws_size,
                              hipStream_t stream) {
    const float* x       = (const float*)d_in[0];
    const int*   ei      = (const int*)d_in[1];   // [2, NE] int32
    const float* lin1_w  = (const float*)d_in[2];
    const float* lin1_b  = (const float*)d_in[3];
    const float* lin2_w  = (const float*)d_in[4];
    const float* lin2_b  = (const float*)d_in[5];
    const float* lin3_w  = (const float*)d_in[6];
    const float* lin3_b  = (const float*)d_in[7];
    const float* conv1_w = (const float*)d_in[8];
    const float* conv1_u = (const float*)d_in[9];
    const float* conv1_c = (const float*)d_in[10];
    const float* conv1_bias = (const float*)d_in[11];
    const float* conv2_w = (const float*)d_in[12];
    const float* conv2_u = (const float*)d_in[13];
    const float* conv2_c = (const float*)d_in[14];
    const float* conv2_bias = (const float*)d_in[15];
    float* out = (float*)d_out;

    // workspace layout (~68 MB, 16B-aligned sections)
    char* p = (char*)d_ws;
    float* a      = (float*)p;           p += (size_t)NN * 64 * 4;   // fp32 a / h
    float* skip   = (float*)p;           p += (size_t)NN * 64 * 4;
    float* tt     = (float*)p;           p += (size_t)NN * 4 * 4;
    ushort16* ab  = (ushort16*)p;        p += (size_t)NN * 64 * 2;   // bf16 a / h
    ushort16* zc  = (ushort16*)p;        p += (size_t)NN * 256 * 2;  // bf16 z
    ushort16* pw12 = (ushort16*)p;       p += 16384 * 2;             // packed [W1|W2]
    ushort16* pwc1 = (ushort16*)p;       p += 16384 * 2;             // packed conv1_w
    ushort16* pwc2 = (ushort16*)p;       p += 16384 * 2;             // packed conv2_w
    ushort16* pwl3 = (ushort16*)p;       p += 4096 * 2;              // packed lin3_w
    int* ssrc     = (int*)p;             p += (size_t)NE * 4;
    int* row_ptr  = (int*)p;             p += (size_t)(NN + 1) * 4;
    int* bcnt     = (int*)p;             p += 256 * 4;               // bucket cursors
    int* bbase    = (int*)p;             p += 256 * 4;               // bucket edge-bases
    uint32* pairs = (uint32*)p;          p += (size_t)NBUCK * BCAP * 4; // padded bins

    // ---- weight pre-pack + bcnt zero (one kernel) + CSR build ----
    k_packall<<<209, 256, 0, stream>>>(lin1_w, lin2_w, conv1_w, conv2_w, lin3_w,
                                       pw12, pwc1, pwc2, pwl3, bcnt);
    k_bin<<<(NE + EPB - 1) / EPB, 256, 0, stream>>>(ei, bcnt, pairs);
    k_bucketscan<<<1, 256, 0, stream>>>(bcnt, bbase, row_ptr);
    k_binscat<<<NBUCK, 256, 0, stream>>>(pairs, bcnt, bbase, row_ptr, ssrc);

    // ---- layer 1 ----
    k_lin12<<<(NN + 63) / 64, 256, 0, stream>>>(x, pw12, lin1_b, lin2_b, a, ab, skip);
    k_t<<<(NN * 4 + 255) / 256, 256, 0, stream>>>(a, conv1_u, tt);
    k_agg<<<(NN + 3) / 4, 256, 0, stream>>>(row_ptr, ssrc, tt, (const uint32*)ab,
                                            conv1_c, (uint4*)zc);
    k_post<<<(NN + 63) / 64, 256, 0, stream>>>(zc, pwc1, conv1_bias, skip, a, ab);

    // ---- layer 2 ---- (h fp32 in a, bf16 in ab)
    k_t<<<(NN * 4 + 255) / 256, 256, 0, stream>>>(a, conv2_u, tt);
    k_lin3m<<<(NN + 63) / 64, 256, 0, stream>>>(ab, pwl3, lin3_b, skip);
    k_agg<<<(NN + 3) / 4, 256, 0, stream>>>(row_ptr, ssrc, tt, (const uint32*)ab,
                                            conv2_c, (uint4*)zc);
    k_post<<<(NN + 63) / 64, 256, 0, stream>>>(zc, pwc2, conv2_bias, skip, out, ab);
}

// Round 3
// 255.441 us; speedup vs baseline: 1.3205x; 1.0587x over previous
//
#include <hip/hip_runtime.h>

#define NN 50000
#define NE 800000
#define NBUCK ((NN + 255) / 256) // 196 dst-buckets of 256 nodes
#define EPB 4096                 // edges per k_bin block (16 per thread)
#define BCAP 8192                // padded per-bucket capacity (mean 4082, max~4.4k)

typedef unsigned int uint32;
typedef unsigned short ushort16;
typedef __attribute__((ext_vector_type(8))) short bf16x8;
typedef __attribute__((ext_vector_type(4))) float f32x4;

__device__ __forceinline__ ushort16 f2bf(float f) {
    uint32 u = __float_as_uint(f);
    u += 0x7fff + ((u >> 16) & 1);      // round-to-nearest-even
    return (ushort16)(u >> 16);
}
__device__ __forceinline__ float bf_lo(uint32 u) {
    return __uint_as_float(u << 16);
}
__device__ __forceinline__ float bf_hi(uint32 u) {
    return __uint_as_float(u & 0xffff0000u);
}
__device__ __forceinline__ bf16x8 pack8(const float4 a, const float4 b) {
    union { bf16x8 v; ushort16 u[8]; } r;
    r.u[0] = f2bf(a.x); r.u[1] = f2bf(a.y); r.u[2] = f2bf(a.z); r.u[3] = f2bf(a.w);
    r.u[4] = f2bf(b.x); r.u[5] = f2bf(b.y); r.u[6] = f2bf(b.z); r.u[7] = f2bf(b.w);
    return r.v;
}

// ---------------------------------------------------------------------------
// Butterfly multi-reduce: 16 values/lane over the 16 m-lanes of a quad.
// After 4 merge steps lane m holds the full sum of element m (no runtime
// indexing, 30 shfl_xor total). Element i = reg*4 + h.
// ---------------------------------------------------------------------------
__device__ __forceinline__ float multireduce16(const float* tl, int m) {
    float t8[8];
#pragma unroll
    for (int i = 0; i < 8; ++i) {
        const float a0 = tl[2 * i], b0 = tl[2 * i + 1];
        const float oa = __shfl_xor(a0, 1, 64), ob = __shfl_xor(b0, 1, 64);
        t8[i] = ((m & 1) == 0) ? (a0 + oa) : (b0 + ob);
    }
    float t4[4];
#pragma unroll
    for (int i = 0; i < 4; ++i) {
        const float a0 = t8[2 * i], b0 = t8[2 * i + 1];
        const float oa = __shfl_xor(a0, 2, 64), ob = __shfl_xor(b0, 2, 64);
        t4[i] = ((m & 2) == 0) ? (a0 + oa) : (b0 + ob);
    }
    float t2[2];
#pragma unroll
    for (int i = 0; i < 2; ++i) {
        const float a0 = t4[2 * i], b0 = t4[2 * i + 1];
        const float oa = __shfl_xor(a0, 4, 64), ob = __shfl_xor(b0, 4, 64);
        t2[i] = ((m & 4) == 0) ? (a0 + oa) : (b0 + ob);
    }
    const float a0 = t2[0], b0 = t2[1];
    const float oa = __shfl_xor(a0, 8, 64), ob = __shfl_xor(b0, 8, 64);
    return ((m & 8) == 0) ? (a0 + oa) : (b0 + ob);
}

// ---------------------------------------------------------------------------
// k_packall: all weight pre-packs fused (fp32 -> bf16 B-fragment order) and
// bcnt zero-init.
// ---------------------------------------------------------------------------
__device__ __forceinline__ ushort16 packp_val(const float* __restrict__ w, int i) {
    const int j  = i & 7;
    const int ln = (i >> 3) & 63;
    const int s  = (i >> 9) & 7;
    const int cc = i >> 12;
    const int k  = s * 32 + ((ln >> 4) * 8) + j;    // zcat idx (k-dim)
    const int n  = cc * 16 + (ln & 15);             // output col
    return f2bf(w[(k >> 2) * 256 + (k & 3) * 64 + n]);
}

__global__ __launch_bounds__(256) void k_packall(
    const float* __restrict__ w1, const float* __restrict__ w2,
    const float* __restrict__ wc1, const float* __restrict__ wc2,
    const float* __restrict__ wl3,
    ushort16* __restrict__ pw12, ushort16* __restrict__ pwc1,
    ushort16* __restrict__ pwc2, ushort16* __restrict__ pwl3,
    int* __restrict__ bcnt)
{
    const int gid = blockIdx.x * 256 + threadIdx.x;
    if (gid < 16384) {
        const int i = gid;
        const int j  = i & 7;
        const int ln = (i >> 3) & 63;
        const int s  = (i >> 9) & 3;
        const int cc = i >> 11;
        const int k  = s * 32 + ((ln >> 4) * 8) + j;    // 0..127
        const int n  = cc * 16 + (ln & 15);             // 0..127
        pw12[i] = f2bf((n < 64) ? w1[k * 64 + n] : w2[k * 64 + (n - 64)]);
    } else if (gid < 32768) {
        pwc1[gid - 16384] = packp_val(wc1, gid - 16384);
    } else if (gid < 49152) {
        pwc2[gid - 32768] = packp_val(wc2, gid - 32768);
    } else if (gid < 53248) {
        const int i = gid - 49152;                      // 0..4095
        const int j  = i & 7;
        const int ln = (i >> 3) & 63;
        const int s  = (i >> 9) & 1;
        const int cc = i >> 10;                         // 0..3
        const int k  = s * 32 + ((ln >> 4) * 8) + j;    // 0..63
        const int n  = cc * 16 + (ln & 15);             // 0..63
        pwl3[i] = f2bf(wl3[k * 64 + n]);
    } else if (gid < 53504) {
        bcnt[gid - 53248] = 0;
    }
}

// ---------------------------------------------------------------------------
// k_lin12 (MFMA): [a_bf16 | skip] = x @ [W1 | W2] + [b1 | b2], with the
// attention projection t = a @ u fused into the epilogue (butterfly reduce
// over m-lanes). fp32 activation buffer is dead and no longer written.
// ---------------------------------------------------------------------------
__global__ __launch_bounds__(256) void k_lin12(
    const float* __restrict__ x, const ushort16* __restrict__ pw,
    const float* __restrict__ b1, const float* __restrict__ b2,
    const float* __restrict__ u,
    ushort16* __restrict__ ab, float* __restrict__ skip,
    float* __restrict__ tOut)
{
    const int tid = threadIdx.x;
    const int lane = tid & 63;
    const int g = tid >> 6;
    const int m = lane & 15;
    const int quad = lane >> 4;
    const int rowBase = blockIdx.x * 64 + g * 16;

    const int arow = min(rowBase + m, NN - 1);
    const float* xr = x + (size_t)arow * 128 + quad * 8;

    f32x4 acc[8];
#pragma unroll
    for (int c = 0; c < 8; ++c)
#pragma unroll
        for (int r = 0; r < 4; ++r) acc[c][r] = 0.f;

#pragma unroll
    for (int s = 0; s < 4; ++s) {
        const float4 xa = *(const float4*)(xr + s * 32);
        const float4 xb = *(const float4*)(xr + s * 32 + 4);
        const bf16x8 af = pack8(xa, xb);
#pragma unroll
        for (int c = 0; c < 8; ++c) {
            const bf16x8 bf = *(const bf16x8*)&pw[((c * 4 + s) * 64 + lane) * 8];
            acc[c] = __builtin_amdgcn_mfma_f32_16x16x32_bf16(af, bf, acc[c], 0, 0, 0);
        }
    }

    float tl[16];
#pragma unroll
    for (int i = 0; i < 16; ++i) tl[i] = 0.f;

#pragma unroll
    for (int c = 0; c < 8; ++c) {
        const int colg = c * 16 + m;
        const float bv = (colg < 64) ? b1[colg] : b2[colg - 64];
#pragma unroll
        for (int reg = 0; reg < 4; ++reg) {
            const float v = acc[c][reg] + bv;
            const int gr = rowBase + quad * 4 + reg;
            if (gr < NN) {
                if (c < 4) ab[gr * 64 + colg] = f2bf(v);
                else       skip[gr * 64 + (colg - 64)] = v;
            }
            if (c < 4) {
                const float4 uv = ((const float4*)u)[colg];
                tl[reg * 4 + 0] += v * uv.x;
                tl[reg * 4 + 1] += v * uv.y;
                tl[reg * 4 + 2] += v * uv.z;
                tl[reg * 4 + 3] += v * uv.w;
            }
        }
    }

    const float tv = multireduce16(tl, m);
    const int gidx = rowBase * 4 + (quad << 4) + m;  // = row*4 + h, contiguous
    if (gidx < NN * 4) tOut[gidx] = tv;
}

// ---------------------------------------------------------------------------
// k_lin3m (MFMA): skip = h_bf16 @ W3 + b3  ([NN,64]@[64,64], K=64).
// ---------------------------------------------------------------------------
__global__ __launch_bounds__(256) void k_lin3m(
    const ushort16* __restrict__ hb, const ushort16* __restrict__ pw,
    const float* __restrict__ b, float* __restrict__ outp)
{
    const int tid = threadIdx.x;
    const int lane = tid & 63;
    const int g = tid >> 6;
    const int m = lane & 15;
    const int quad = lane >> 4;
    const int rowBase = blockIdx.x * 64 + g * 16;

    const int arow = min(rowBase + m, NN - 1);
    const ushort16* zrow = hb + (size_t)arow * 64 + quad * 8;

    f32x4 acc[4];
#pragma unroll
    for (int c = 0; c < 4; ++c)
#pragma unroll
        for (int r = 0; r < 4; ++r) acc[c][r] = 0.f;

#pragma unroll
    for (int s = 0; s < 2; ++s) {
        const bf16x8 af = *(const bf16x8*)(zrow + s * 32);
#pragma unroll
        for (int c = 0; c < 4; ++c) {
            const bf16x8 bf = *(const bf16x8*)&pw[((c * 2 + s) * 64 + lane) * 8];
            acc[c] = __builtin_amdgcn_mfma_f32_16x16x32_bf16(af, bf, acc[c], 0, 0, 0);
        }
    }

#pragma unroll
    for (int c = 0; c < 4; ++c) {
        const int colg = c * 16 + m;
        const float bv = b[colg];
#pragma unroll
        for (int reg = 0; reg < 4; ++reg) {
            const int gr = rowBase + quad * 4 + reg;
            if (gr < NN) outp[gr * 64 + colg] = acc[c][reg] + bv;
        }
    }
}

// ---------------------------------------------------------------------------
// CSR build: k_bin appends edges into bucket-PADDED `pairs` (cursor bcnt[b]
// from 0). k_binscat re-derives bucket edge-bases itself (196-entry scan,
// L2-broadcast), recovers per-node degrees with an LDS histogram + scan,
// emits row_ptr, and scatters ssrc within its ~16KB L2-resident window.
// ---------------------------------------------------------------------------
__global__ __launch_bounds__(256) void k_bin(const int* __restrict__ ei,
                                             int* __restrict__ bcnt,
                                             uint32* __restrict__ pairs)
{
    __shared__ int hist[NBUCK];
    __shared__ int gbase[NBUCK];
    const int t = threadIdx.x;
    const int base = blockIdx.x * EPB;

    for (int b = t; b < NBUCK; b += 256) hist[b] = 0;
    __syncthreads();

    uint32 pk[16];
    int bk[16], rk[16];
#pragma unroll
    for (int k = 0; k < 16; ++k) {
        const int e = base + k * 256 + t;
        if (e < NE) {
            const int s = ei[e];
            const int d = ei[NE + e];
            bk[k] = d >> 8;
            pk[k] = (uint32)s | ((uint32)(d & 255) << 16);
            rk[k] = atomicAdd(&hist[bk[k]], 1);
        }
    }
    __syncthreads();

    for (int b = t; b < NBUCK; b += 256)
        gbase[b] = hist[b] ? atomicAdd(&bcnt[b], hist[b]) : 0;
    __syncthreads();

#pragma unroll
    for (int k = 0; k < 16; ++k) {
        const int e = base + k * 256 + t;
        if (e < NE) pairs[(size_t)bk[k] * BCAP + gbase[bk[k]] + rk[k]] = pk[k];
    }
}

__global__ __launch_bounds__(256) void k_binscat(const uint32* __restrict__ pairs,
                                                 const int* __restrict__ bcnt,
                                                 int* __restrict__ row_ptr,
                                                 int* __restrict__ ssrc)
{
    __shared__ int sb[256];
    __shared__ int hist[256];
    __shared__ int s[256];
    __shared__ int lptr[256];
    __shared__ int lcur[256];
    const int b = blockIdx.x;
    const int t = threadIdx.x;
    const int total = bcnt[b];
    const uint32* pb = pairs + (size_t)b * BCAP;

    // bucket-level exclusive base via block-local scan of all bucket counts
    sb[t] = (t < NBUCK) ? bcnt[t] : 0;
    __syncthreads();
    for (int off = 1; off < 256; off <<= 1) {
        const int v = (t >= off) ? sb[t - off] : 0;
        __syncthreads();
        sb[t] += v;
        __syncthreads();
    }
    const int base = sb[b] - total;
    if (b == 0 && t == 0) row_ptr[NN] = NE;

    hist[t] = 0;
    __syncthreads();
    for (int e = t; e < total; e += 256) atomicAdd(&hist[pb[e] >> 16], 1);
    __syncthreads();

    const int v = hist[t];
    s[t] = v;
    __syncthreads();
    for (int off = 1; off < 256; off <<= 1) {
        const int u = (t >= off) ? s[t - off] : 0;
        __syncthreads();
        s[t] += u;
        __syncthreads();
    }
    const int excl = base + s[t] - v;
    lptr[t] = excl;
    lcur[t] = 0;
    const int n = (b << 8) + t;
    if (n < NN) row_ptr[n] = excl;
    __syncthreads();

    for (int e = t; e < total; e += 256) {
        const uint32 p = pb[e];
        const int d = p >> 16;
        const int r = atomicAdd(&lcur[d], 1);
        ssrc[lptr[d] + r] = (int)(p & 0xffffu);
    }
}

// ---------------------------------------------------------------------------
// k_agg: one wave per dst node; TWO edges per iteration (lane halves).
// ---------------------------------------------------------------------------
__global__ __launch_bounds__(256) void k_agg(
    const int* __restrict__ row_ptr, const int* __restrict__ ssrc,
    const float* __restrict__ t, const uint32* __restrict__ abu,
    const float* __restrict__ c, uint4* __restrict__ zcat4)
{
    const int lane = threadIdx.x & 63;
    const int node = (blockIdx.x * 256 + threadIdx.x) >> 6;
    if (node >= NN) return;

    const int half = lane >> 5;
    const int u = lane & 31;

    const int r0 = row_ptr[node];
    const int r1 = row_ptr[node + 1];
    const int deg = r1 - r0;
    const float invdeg = (deg > 0) ? 1.f / (float)deg : 0.f;

    const float4 tc = *(const float4*)c;
    const float4 td = ((const float4*)t)[node];

    float z00 = 0.f, z01 = 0.f, z10 = 0.f, z11 = 0.f;
    float z20 = 0.f, z21 = 0.f, z30 = 0.f, z31 = 0.f;

    for (int base = r0; base < r1; base += 64) {
        const int m = min(64, r1 - base);

        int src = 0;
        float q0 = 0.f, q1 = 0.f, q2 = 0.f, q3 = 0.f;
        if (lane < m) {
            src = ssrc[base + lane];
            const float4 ts = ((const float4*)t)[src];
            const float l0 = ts.x - td.x + tc.x;
            const float l1 = ts.y - td.y + tc.y;
            const float l2 = ts.z - td.z + tc.z;
            const float l3 = ts.w - td.w + tc.w;
            const float mx = fmaxf(fmaxf(l0, l1), fmaxf(l2, l3));
            const float e0 = __expf(l0 - mx);
            const float e1 = __expf(l1 - mx);
            const float e2 = __expf(l2 - mx);
            const float e3 = __expf(l3 - mx);
            const float s = invdeg / (e0 + e1 + e2 + e3);
            q0 = e0 * s; q1 = e1 * s; q2 = e2 * s; q3 = e3 * s;
        }

        int e = 0;
        for (; e + 7 < m; e += 8) {
#pragma unroll
            for (int k = 0; k < 8; k += 2) {
                const int idx = e + k + half;
                const int se = __shfl(src, idx, 64);
                const float a0 = __shfl(q0, idx, 64);
                const float a1 = __shfl(q1, idx, 64);
                const float a2 = __shfl(q2, idx, 64);
                const float a3 = __shfl(q3, idx, 64);
                const uint32 av = abu[se * 32 + u];
                const float v0 = bf_lo(av), v1 = bf_hi(av);
                z00 += a0 * v0; z01 += a0 * v1;
                z10 += a1 * v0; z11 += a1 * v1;
                z20 += a2 * v0; z21 += a2 * v1;
                z30 += a3 * v0; z31 += a3 * v1;
            }
        }
        for (; e + 1 < m; e += 2) {
            const int idx = e + half;
            const int se = __shfl(src, idx, 64);
            const float a0 = __shfl(q0, idx, 64);
            const float a1 = __shfl(q1, idx, 64);
            const float a2 = __shfl(q2, idx, 64);
            const float a3 = __shfl(q3, idx, 64);
            const uint32 av = abu[se * 32 + u];
            const float v0 = bf_lo(av), v1 = bf_hi(av);
            z00 += a0 * v0; z01 += a0 * v1;
            z10 += a1 * v0; z11 += a1 * v1;
            z20 += a2 * v0; z21 += a2 * v1;
            z30 += a3 * v0; z31 += a3 * v1;
        }
        if (e < m) {
            const int se = __shfl(src, e, 64);
            const float a0 = __shfl(q0, e, 64);
            const float a1 = __shfl(q1, e, 64);
            const float a2 = __shfl(q2, e, 64);
            const float a3 = __shfl(q3, e, 64);
            if (half == 0) {
                const uint32 av = abu[se * 32 + u];
                const float v0 = bf_lo(av), v1 = bf_hi(av);
                z00 += a0 * v0; z01 += a0 * v1;
                z10 += a1 * v0; z11 += a1 * v1;
                z20 += a2 * v0; z21 += a2 * v1;
                z30 += a3 * v0; z31 += a3 * v1;
            }
        }
    }

    z00 += __shfl_xor(z00, 32, 64); z01 += __shfl_xor(z01, 32, 64);
    z10 += __shfl_xor(z10, 32, 64); z11 += __shfl_xor(z11, 32, 64);
    z20 += __shfl_xor(z20, 32, 64); z21 += __shfl_xor(z21, 32, 64);
    z30 += __shfl_xor(z30, 32, 64); z31 += __shfl_xor(z31, 32, 64);

    if (half == 0) {
        uint4 pk;
        pk.x = (uint32)f2bf(z00) | ((uint32)f2bf(z10) << 16);
        pk.y = (uint32)f2bf(z20) | ((uint32)f2bf(z30) << 16);
        pk.z = (uint32)f2bf(z01) | ((uint32)f2bf(z11) << 16);
        pk.w = (uint32)f2bf(z21) | ((uint32)f2bf(z31) << 16);
        zcat4[node * 32 + u] = pk;
    }
}

// ---------------------------------------------------------------------------
// k_post (MFMA): out = relu(zcat @ Wp + bias + skip); optional fp32 store,
// optional bf16 store, optional fused t = out @ u (layer-2 attention proj).
// ---------------------------------------------------------------------------
__global__ __launch_bounds__(256) void k_post(
    const ushort16* __restrict__ zcat, const ushort16* __restrict__ pw,
    const float* __restrict__ bias, const float* __restrict__ skip,
    float* __restrict__ out, ushort16* __restrict__ outb,
    const float* __restrict__ u, float* __restrict__ tOut)
{
    const int tid = threadIdx.x;
    const int lane = tid & 63;
    const int g = tid >> 6;
    const int m = lane & 15;
    const int quad = lane >> 4;
    const int rowBase = blockIdx.x * 64 + g * 16;

    const int arow = min(rowBase + m, NN - 1);
    const ushort16* zrow = zcat + (size_t)arow * 256 + quad * 8;

    f32x4 acc[4];
#pragma unroll
    for (int c = 0; c < 4; ++c)
#pragma unroll
        for (int r = 0; r < 4; ++r) acc[c][r] = 0.f;

#pragma unroll
    for (int s = 0; s < 8; ++s) {
        const bf16x8 af = *(const bf16x8*)(zrow + s * 32);
#pragma unroll
        for (int c = 0; c < 4; ++c) {
            const bf16x8 bf = *(const bf16x8*)&pw[((c * 8 + s) * 64 + lane) * 8];
            acc[c] = __builtin_amdgcn_mfma_f32_16x16x32_bf16(af, bf, acc[c], 0, 0, 0);
        }
    }

    float tl[16];
#pragma unroll
    for (int i = 0; i < 16; ++i) tl[i] = 0.f;

#pragma unroll
    for (int c = 0; c < 4; ++c) {
        const int colg = c * 16 + m;
        const float bv = bias[colg];
#pragma unroll
        for (int reg = 0; reg < 4; ++reg) {
            const int gr = rowBase + quad * 4 + reg;
            const int grc = min(gr, NN - 1);
            const float v = fmaxf(acc[c][reg] + bv + skip[grc * 64 + colg], 0.f);
            if (gr < NN) {
                if (out)  out[gr * 64 + colg]  = v;
                if (outb) outb[gr * 64 + colg] = f2bf(v);
            }
            if (tOut) {
                const float4 uv = ((const float4*)u)[colg];
                tl[reg * 4 + 0] += v * uv.x;
                tl[reg * 4 + 1] += v * uv.y;
                tl[reg * 4 + 2] += v * uv.z;
                tl[reg * 4 + 3] += v * uv.w;
            }
        }
    }

    if (tOut) {
        const float tv = multireduce16(tl, m);
        const int gidx = rowBase * 4 + (quad << 4) + m;
        if (gidx < NN * 4) tOut[gidx] = tv;
    }
}

extern "C" void kernel_launch(void* const* d_in, const int* in_sizes, int n_in,
                              void* d_out, int out_size, void* d_ws, size_t ws_size,
                              hipStream_t stream) {
    const float* x       = (const float*)d_in[0];
    const int*   ei      = (const int*)d_in[1];   // [2, NE] int32
    const float* lin1_w  = (const float*)d_in[2];
    const float* lin1_b  = (const float*)d_in[3];
    const float* lin2_w  = (const float*)d_in[4];
    const float* lin2_b  = (const float*)d_in[5];
    const float* lin3_w  = (const float*)d_in[6];
    const float* lin3_b  = (const float*)d_in[7];
    const float* conv1_w = (const float*)d_in[8];
    const float* conv1_u = (const float*)d_in[9];
    const float* conv1_c = (const float*)d_in[10];
    const float* conv1_bias = (const float*)d_in[11];
    const float* conv2_w = (const float*)d_in[12];
    const float* conv2_u = (const float*)d_in[13];
    const float* conv2_c = (const float*)d_in[14];
    const float* conv2_bias = (const float*)d_in[15];
    float* out = (float*)d_out;

    // workspace layout (~56 MB, 16B-aligned sections)
    char* p = (char*)d_ws;
    float* skip   = (float*)p;           p += (size_t)NN * 64 * 4;
    float* tt     = (float*)p;           p += (size_t)NN * 4 * 4;
    ushort16* ab  = (ushort16*)p;        p += (size_t)NN * 64 * 2;   // bf16 a / h
    ushort16* zc  = (ushort16*)p;        p += (size_t)NN * 256 * 2;  // bf16 z
    ushort16* pw12 = (ushort16*)p;       p += 16384 * 2;             // packed [W1|W2]
    ushort16* pwc1 = (ushort16*)p;       p += 16384 * 2;             // packed conv1_w
    ushort16* pwc2 = (ushort16*)p;       p += 16384 * 2;             // packed conv2_w
    ushort16* pwl3 = (ushort16*)p;       p += 4096 * 2;              // packed lin3_w
    int* ssrc     = (int*)p;             p += (size_t)NE * 4;
    int* row_ptr  = (int*)p;             p += (size_t)(NN + 1) * 4;
    int* bcnt     = (int*)p;             p += 256 * 4;               // bucket cursors
    uint32* pairs = (uint32*)p;          p += (size_t)NBUCK * BCAP * 4; // padded bins

    // ---- weight pre-pack + bcnt zero + CSR build (3 dispatches) ----
    k_packall<<<209, 256, 0, stream>>>(lin1_w, lin2_w, conv1_w, conv2_w, lin3_w,
                                       pw12, pwc1, pwc2, pwl3, bcnt);
    k_bin<<<(NE + EPB - 1) / EPB, 256, 0, stream>>>(ei, bcnt, pairs);
    k_binscat<<<NBUCK, 256, 0, stream>>>(pairs, bcnt, row_ptr, ssrc);

    // ---- layer 1 ----
    k_lin12<<<(NN + 63) / 64, 256, 0, stream>>>(x, pw12, lin1_b, lin2_b, conv1_u,
                                                ab, skip, tt);
    k_agg<<<(NN + 3) / 4, 256, 0, stream>>>(row_ptr, ssrc, tt, (const uint32*)ab,
                                            conv1_c, (uint4*)zc);
    k_post<<<(NN + 63) / 64, 256, 0, stream>>>(zc, pwc1, conv1_bias, skip,
                                               nullptr, ab, conv2_u, tt);

    // ---- layer 2 ---- (h bf16 in ab, t2 already in tt)
    k_lin3m<<<(NN + 63) / 64, 256, 0, stream>>>(ab, pwl3, lin3_b, skip);
    k_agg<<<(NN + 3) / 4, 256, 0, stream>>>(row_ptr, ssrc, tt, (const uint32*)ab,
                                            conv2_c, (uint4*)zc);
    k_post<<<(NN + 63) / 64, 256, 0, stream>>>(zc, pwc2, conv2_bias, skip,
                                               out, nullptr, nullptr, nullptr);
}

// Round 4
// 250.391 us; speedup vs baseline: 1.3472x; 1.0202x over previous
//
#include <hip/hip_runtime.h>

#define NN 50000
#define NE 800000
#define NBUCK ((NN + 255) / 256) // 196 dst-buckets of 256 nodes
#define EPB 4096                 // edges per k_bin block (16 per thread)
#define BCAP 8192                // padded per-bucket capacity (mean 4082, max~4.4k)

typedef unsigned int uint32;
typedef unsigned short ushort16;
typedef __attribute__((ext_vector_type(8))) short bf16x8;
typedef __attribute__((ext_vector_type(4))) float f32x4;

__device__ __forceinline__ ushort16 f2bf(float f) {
    uint32 u = __float_as_uint(f);
    u += 0x7fff + ((u >> 16) & 1);      // round-to-nearest-even
    return (ushort16)(u >> 16);
}
__device__ __forceinline__ float bf_lo(uint32 u) {
    return __uint_as_float(u << 16);
}
__device__ __forceinline__ float bf_hi(uint32 u) {
    return __uint_as_float(u & 0xffff0000u);
}
__device__ __forceinline__ bf16x8 pack8(const float4 a, const float4 b) {
    union { bf16x8 v; ushort16 u[8]; } r;
    r.u[0] = f2bf(a.x); r.u[1] = f2bf(a.y); r.u[2] = f2bf(a.z); r.u[3] = f2bf(a.w);
    r.u[4] = f2bf(b.x); r.u[5] = f2bf(b.y); r.u[6] = f2bf(b.z); r.u[7] = f2bf(b.w);
    return r.v;
}

// ---------------------------------------------------------------------------
// Butterfly multi-reduce: 16 values/lane over the 16 m-lanes of a quad.
// After 4 merge steps lane m holds the full sum of element m.
// ---------------------------------------------------------------------------
__device__ __forceinline__ float multireduce16(const float* tl, int m) {
    float t8[8];
#pragma unroll
    for (int i = 0; i < 8; ++i) {
        const float a0 = tl[2 * i], b0 = tl[2 * i + 1];
        const float oa = __shfl_xor(a0, 1, 64), ob = __shfl_xor(b0, 1, 64);
        t8[i] = ((m & 1) == 0) ? (a0 + oa) : (b0 + ob);
    }
    float t4[4];
#pragma unroll
    for (int i = 0; i < 4; ++i) {
        const float a0 = t8[2 * i], b0 = t8[2 * i + 1];
        const float oa = __shfl_xor(a0, 2, 64), ob = __shfl_xor(b0, 2, 64);
        t4[i] = ((m & 2) == 0) ? (a0 + oa) : (b0 + ob);
    }
    float t2[2];
#pragma unroll
    for (int i = 0; i < 2; ++i) {
        const float a0 = t4[2 * i], b0 = t4[2 * i + 1];
        const float oa = __shfl_xor(a0, 4, 64), ob = __shfl_xor(b0, 4, 64);
        t2[i] = ((m & 4) == 0) ? (a0 + oa) : (b0 + ob);
    }
    const float a0 = t2[0], b0 = t2[1];
    const float oa = __shfl_xor(a0, 8, 64), ob = __shfl_xor(b0, 8, 64);
    return ((m & 8) == 0) ? (a0 + oa) : (b0 + ob);
}

// ---------------------------------------------------------------------------
// k_packall: all weight pre-packs fused (fp32 -> bf16 B-fragment order) and
// bcnt zero-init.
// ---------------------------------------------------------------------------
__device__ __forceinline__ ushort16 packp_val(const float* __restrict__ w, int i) {
    const int j  = i & 7;
    const int ln = (i >> 3) & 63;
    const int s  = (i >> 9) & 7;
    const int cc = i >> 12;
    const int k  = s * 32 + ((ln >> 4) * 8) + j;    // zcat idx (k-dim)
    const int n  = cc * 16 + (ln & 15);             // output col
    return f2bf(w[(k >> 2) * 256 + (k & 3) * 64 + n]);
}

__global__ __launch_bounds__(256) void k_packall(
    const float* __restrict__ w1, const float* __restrict__ w2,
    const float* __restrict__ wc1, const float* __restrict__ wc2,
    const float* __restrict__ wl3,
    ushort16* __restrict__ pw12, ushort16* __restrict__ pwc1,
    ushort16* __restrict__ pwc2, ushort16* __restrict__ pwl3,
    int* __restrict__ bcnt)
{
    const int gid = blockIdx.x * 256 + threadIdx.x;
    if (gid < 16384) {
        const int i = gid;
        const int j  = i & 7;
        const int ln = (i >> 3) & 63;
        const int s  = (i >> 9) & 3;
        const int cc = i >> 11;
        const int k  = s * 32 + ((ln >> 4) * 8) + j;    // 0..127
        const int n  = cc * 16 + (ln & 15);             // 0..127
        pw12[i] = f2bf((n < 64) ? w1[k * 64 + n] : w2[k * 64 + (n - 64)]);
    } else if (gid < 32768) {
        pwc1[gid - 16384] = packp_val(wc1, gid - 16384);
    } else if (gid < 49152) {
        pwc2[gid - 32768] = packp_val(wc2, gid - 32768);
    } else if (gid < 53248) {
        const int i = gid - 49152;                      // 0..4095
        const int j  = i & 7;
        const int ln = (i >> 3) & 63;
        const int s  = (i >> 9) & 1;
        const int cc = i >> 10;                         // 0..3
        const int k  = s * 32 + ((ln >> 4) * 8) + j;    // 0..63
        const int n  = cc * 16 + (ln & 15);             // 0..63
        pwl3[i] = f2bf(wl3[k * 64 + n]);
    } else if (gid < 53504) {
        bcnt[gid - 53248] = 0;
    }
}

// ---------------------------------------------------------------------------
// k_lin12 (MFMA): [a_bf16 | skip] = x @ [W1 | W2] + [b1 | b2], with the
// attention projection t = a @ u fused into the epilogue.
// ---------------------------------------------------------------------------
__global__ __launch_bounds__(256) void k_lin12(
    const float* __restrict__ x, const ushort16* __restrict__ pw,
    const float* __restrict__ b1, const float* __restrict__ b2,
    const float* __restrict__ u,
    ushort16* __restrict__ ab, float* __restrict__ skip,
    float* __restrict__ tOut)
{
    const int tid = threadIdx.x;
    const int lane = tid & 63;
    const int g = tid >> 6;
    const int m = lane & 15;
    const int quad = lane >> 4;
    const int rowBase = blockIdx.x * 64 + g * 16;

    const int arow = min(rowBase + m, NN - 1);
    const float* xr = x + (size_t)arow * 128 + quad * 8;

    f32x4 acc[8];
#pragma unroll
    for (int c = 0; c < 8; ++c)
#pragma unroll
        for (int r = 0; r < 4; ++r) acc[c][r] = 0.f;

#pragma unroll
    for (int s = 0; s < 4; ++s) {
        const float4 xa = *(const float4*)(xr + s * 32);
        const float4 xb = *(const float4*)(xr + s * 32 + 4);
        const bf16x8 af = pack8(xa, xb);
#pragma unroll
        for (int c = 0; c < 8; ++c) {
            const bf16x8 bf = *(const bf16x8*)&pw[((c * 4 + s) * 64 + lane) * 8];
            acc[c] = __builtin_amdgcn_mfma_f32_16x16x32_bf16(af, bf, acc[c], 0, 0, 0);
        }
    }

    float tl[16];
#pragma unroll
    for (int i = 0; i < 16; ++i) tl[i] = 0.f;

#pragma unroll
    for (int c = 0; c < 8; ++c) {
        const int colg = c * 16 + m;
        const float bv = (colg < 64) ? b1[colg] : b2[colg - 64];
#pragma unroll
        for (int reg = 0; reg < 4; ++reg) {
            const float v = acc[c][reg] + bv;
            const int gr = rowBase + quad * 4 + reg;
            if (gr < NN) {
                if (c < 4) ab[gr * 64 + colg] = f2bf(v);
                else       skip[gr * 64 + (colg - 64)] = v;
            }
            if (c < 4) {
                const float4 uv = ((const float4*)u)[colg];
                tl[reg * 4 + 0] += v * uv.x;
                tl[reg * 4 + 1] += v * uv.y;
                tl[reg * 4 + 2] += v * uv.z;
                tl[reg * 4 + 3] += v * uv.w;
            }
        }
    }

    const float tv = multireduce16(tl, m);
    const int gidx = rowBase * 4 + (quad << 4) + m;  // = row*4 + h, contiguous
    if (gidx < NN * 4) tOut[gidx] = tv;
}

// ---------------------------------------------------------------------------
// k_lin3m (MFMA): skip = h_bf16 @ W3 + b3  ([NN,64]@[64,64], K=64).
// ---------------------------------------------------------------------------
__global__ __launch_bounds__(256) void k_lin3m(
    const ushort16* __restrict__ hb, const ushort16* __restrict__ pw,
    const float* __restrict__ b, float* __restrict__ outp)
{
    const int tid = threadIdx.x;
    const int lane = tid & 63;
    const int g = tid >> 6;
    const int m = lane & 15;
    const int quad = lane >> 4;
    const int rowBase = blockIdx.x * 64 + g * 16;

    const int arow = min(rowBase + m, NN - 1);
    const ushort16* zrow = hb + (size_t)arow * 64 + quad * 8;

    f32x4 acc[4];
#pragma unroll
    for (int c = 0; c < 4; ++c)
#pragma unroll
        for (int r = 0; r < 4; ++r) acc[c][r] = 0.f;

#pragma unroll
    for (int s = 0; s < 2; ++s) {
        const bf16x8 af = *(const bf16x8*)(zrow + s * 32);
#pragma unroll
        for (int c = 0; c < 4; ++c) {
            const bf16x8 bf = *(const bf16x8*)&pw[((c * 2 + s) * 64 + lane) * 8];
            acc[c] = __builtin_amdgcn_mfma_f32_16x16x32_bf16(af, bf, acc[c], 0, 0, 0);
        }
    }

#pragma unroll
    for (int c = 0; c < 4; ++c) {
        const int colg = c * 16 + m;
        const float bv = b[colg];
#pragma unroll
        for (int reg = 0; reg < 4; ++reg) {
            const int gr = rowBase + quad * 4 + reg;
            if (gr < NN) outp[gr * 64 + colg] = acc[c][reg] + bv;
        }
    }
}

// ---------------------------------------------------------------------------
// CSR build: k_bin appends edges into bucket-PADDED `pairs`; k_binscat
// derives bucket bases + per-node row_ptr in-block and scatters ssrc.
// ---------------------------------------------------------------------------
__global__ __launch_bounds__(256) void k_bin(const int* __restrict__ ei,
                                             int* __restrict__ bcnt,
                                             uint32* __restrict__ pairs)
{
    __shared__ int hist[NBUCK];
    __shared__ int gbase[NBUCK];
    const int t = threadIdx.x;
    const int base = blockIdx.x * EPB;

    for (int b = t; b < NBUCK; b += 256) hist[b] = 0;
    __syncthreads();

    uint32 pk[16];
    int bk[16], rk[16];
#pragma unroll
    for (int k = 0; k < 16; ++k) {
        const int e = base + k * 256 + t;
        if (e < NE) {
            const int s = ei[e];
            const int d = ei[NE + e];
            bk[k] = d >> 8;
            pk[k] = (uint32)s | ((uint32)(d & 255) << 16);
            rk[k] = atomicAdd(&hist[bk[k]], 1);
        }
    }
    __syncthreads();

    for (int b = t; b < NBUCK; b += 256)
        gbase[b] = hist[b] ? atomicAdd(&bcnt[b], hist[b]) : 0;
    __syncthreads();

#pragma unroll
    for (int k = 0; k < 16; ++k) {
        const int e = base + k * 256 + t;
        if (e < NE) pairs[(size_t)bk[k] * BCAP + gbase[bk[k]] + rk[k]] = pk[k];
    }
}

__global__ __launch_bounds__(256) void k_binscat(const uint32* __restrict__ pairs,
                                                 const int* __restrict__ bcnt,
                                                 int* __restrict__ row_ptr,
                                                 int* __restrict__ ssrc)
{
    __shared__ int sb[256];
    __shared__ int hist[256];
    __shared__ int s[256];
    __shared__ int lptr[256];
    __shared__ int lcur[256];
    const int b = blockIdx.x;
    const int t = threadIdx.x;
    const int total = bcnt[b];
    const uint32* pb = pairs + (size_t)b * BCAP;

    // bucket-level exclusive base via block-local scan of all bucket counts
    sb[t] = (t < NBUCK) ? bcnt[t] : 0;
    __syncthreads();
    for (int off = 1; off < 256; off <<= 1) {
        const int v = (t >= off) ? sb[t - off] : 0;
        __syncthreads();
        sb[t] += v;
        __syncthreads();
    }
    const int base = sb[b] - total;
    if (b == 0 && t == 0) row_ptr[NN] = NE;

    hist[t] = 0;
    __syncthreads();
    for (int e = t; e < total; e += 256) atomicAdd(&hist[pb[e] >> 16], 1);
    __syncthreads();

    const int v = hist[t];
    s[t] = v;
    __syncthreads();
    for (int off = 1; off < 256; off <<= 1) {
        const int u = (t >= off) ? s[t - off] : 0;
        __syncthreads();
        s[t] += u;
        __syncthreads();
    }
    const int excl = base + s[t] - v;
    lptr[t] = excl;
    lcur[t] = 0;
    const int n = (b << 8) + t;
    if (n < NN) row_ptr[n] = excl;
    __syncthreads();

    for (int e = t; e < total; e += 256) {
        const uint32 p = pb[e];
        const int d = p >> 16;
        const int r = atomicAdd(&lcur[d], 1);
        ssrc[lptr[d] + r] = (int)(p & 0xffffu);
    }
}

// ---------------------------------------------------------------------------
// k_aggpost: FUSED aggregation + post-GEMM. One block = 16 consecutive dst
// nodes; 4 waves x 4 sequential nodes. Per node: softmax attention +
// bf16-weighted aggregation (identical to old k_agg), zcat row written to
// LDS (XOR-swizzled). Barrier. Then the 16x256 LDS tile is the MFMA A-tile:
// wave w computes output cols w*16..+15 (8x mfma_16x16x32), + bias + skip +
// relu; optional fp32 / bf16 stores; optional fused t = out @ u with
// cross-wave LDS reduction (fp32 precision preserved).
// ---------------------------------------------------------------------------
__global__ __launch_bounds__(256) void k_aggpost(
    const int* __restrict__ row_ptr, const int* __restrict__ ssrc,
    const float* __restrict__ t, const uint32* __restrict__ abu,
    const float* __restrict__ c,
    const ushort16* __restrict__ pw, const float* __restrict__ bias,
    const float* __restrict__ skip,
    float* __restrict__ out, ushort16* __restrict__ outb,
    const float* __restrict__ uproj, float* __restrict__ tOut)
{
    __shared__ char zl[16 * 512];       // 16 nodes x 256 bf16, XOR-swizzled
    __shared__ float t_lds[4][64];

    const int tid = threadIdx.x;
    const int lane = tid & 63;
    const int w = tid >> 6;
    const int half = lane >> 5;
    const int u = lane & 31;
    const int nodeBase = blockIdx.x * 16;

    const float4 tc = *(const float4*)c;

    for (int nn = 0; nn < 4; ++nn) {
        const int nloc = w * 4 + nn;
        const int node = nodeBase + nloc;

        const int r0 = row_ptr[node];
        const int r1 = row_ptr[node + 1];
        const int deg = r1 - r0;
        const float invdeg = (deg > 0) ? 1.f / (float)deg : 0.f;
        const float4 td = ((const float4*)t)[node];

        float z00 = 0.f, z01 = 0.f, z10 = 0.f, z11 = 0.f;
        float z20 = 0.f, z21 = 0.f, z30 = 0.f, z31 = 0.f;

        for (int base = r0; base < r1; base += 64) {
            const int cnt = min(64, r1 - base);

            int src = 0;
            float q0 = 0.f, q1 = 0.f, q2 = 0.f, q3 = 0.f;
            if (lane < cnt) {
                src = ssrc[base + lane];
                const float4 ts = ((const float4*)t)[src];
                const float l0 = ts.x - td.x + tc.x;
                const float l1 = ts.y - td.y + tc.y;
                const float l2 = ts.z - td.z + tc.z;
                const float l3 = ts.w - td.w + tc.w;
                const float mx = fmaxf(fmaxf(l0, l1), fmaxf(l2, l3));
                const float e0 = __expf(l0 - mx);
                const float e1 = __expf(l1 - mx);
                const float e2 = __expf(l2 - mx);
                const float e3 = __expf(l3 - mx);
                const float sden = invdeg / (e0 + e1 + e2 + e3);
                q0 = e0 * sden; q1 = e1 * sden; q2 = e2 * sden; q3 = e3 * sden;
            }

            int e = 0;
            for (; e + 7 < cnt; e += 8) {
#pragma unroll
                for (int k = 0; k < 8; k += 2) {
                    const int idx = e + k + half;
                    const int se = __shfl(src, idx, 64);
                    const float a0 = __shfl(q0, idx, 64);
                    const float a1 = __shfl(q1, idx, 64);
                    const float a2 = __shfl(q2, idx, 64);
                    const float a3 = __shfl(q3, idx, 64);
                    const uint32 av = abu[se * 32 + u];
                    const float v0 = bf_lo(av), v1 = bf_hi(av);
                    z00 += a0 * v0; z01 += a0 * v1;
                    z10 += a1 * v0; z11 += a1 * v1;
                    z20 += a2 * v0; z21 += a2 * v1;
                    z30 += a3 * v0; z31 += a3 * v1;
                }
            }
            for (; e + 1 < cnt; e += 2) {
                const int idx = e + half;
                const int se = __shfl(src, idx, 64);
                const float a0 = __shfl(q0, idx, 64);
                const float a1 = __shfl(q1, idx, 64);
                const float a2 = __shfl(q2, idx, 64);
                const float a3 = __shfl(q3, idx, 64);
                const uint32 av = abu[se * 32 + u];
                const float v0 = bf_lo(av), v1 = bf_hi(av);
                z00 += a0 * v0; z01 += a0 * v1;
                z10 += a1 * v0; z11 += a1 * v1;
                z20 += a2 * v0; z21 += a2 * v1;
                z30 += a3 * v0; z31 += a3 * v1;
            }
            if (e < cnt) {
                const int se = __shfl(src, e, 64);
                const float a0 = __shfl(q0, e, 64);
                const float a1 = __shfl(q1, e, 64);
                const float a2 = __shfl(q2, e, 64);
                const float a3 = __shfl(q3, e, 64);
                if (half == 0) {
                    const uint32 av = abu[se * 32 + u];
                    const float v0 = bf_lo(av), v1 = bf_hi(av);
                    z00 += a0 * v0; z01 += a0 * v1;
                    z10 += a1 * v0; z11 += a1 * v1;
                    z20 += a2 * v0; z21 += a2 * v1;
                    z30 += a3 * v0; z31 += a3 * v1;
                }
            }
        }

        z00 += __shfl_xor(z00, 32, 64); z01 += __shfl_xor(z01, 32, 64);
        z10 += __shfl_xor(z10, 32, 64); z11 += __shfl_xor(z11, 32, 64);
        z20 += __shfl_xor(z20, 32, 64); z21 += __shfl_xor(z21, 32, 64);
        z30 += __shfl_xor(z30, 32, 64); z31 += __shfl_xor(z31, 32, 64);

        if (half == 0) {
            uint4 pk;
            pk.x = (uint32)f2bf(z00) | ((uint32)f2bf(z10) << 16);
            pk.y = (uint32)f2bf(z20) | ((uint32)f2bf(z30) << 16);
            pk.z = (uint32)f2bf(z01) | ((uint32)f2bf(z11) << 16);
            pk.w = (uint32)f2bf(z21) | ((uint32)f2bf(z31) << 16);
            *(uint4*)(zl + nloc * 512 + ((u * 16) ^ ((nloc & 7) << 4))) = pk;
        }
    }
    __syncthreads();

    // ---- post-GEMM from LDS (A: 16 nodes x 256; wave w -> cols w*16..+15) ----
    const int m = lane & 15;
    const int quad = lane >> 4;

    f32x4 acc;
#pragma unroll
    for (int r = 0; r < 4; ++r) acc[r] = 0.f;

#pragma unroll
    for (int s = 0; s < 8; ++s) {
        const bf16x8 af = *(const bf16x8*)(zl + m * 512 +
                            ((s * 64 + quad * 16) ^ ((m & 7) << 4)));
        const bf16x8 bf = *(const bf16x8*)&pw[((w * 8 + s) * 64 + lane) * 8];
        acc = __builtin_amdgcn_mfma_f32_16x16x32_bf16(af, bf, acc, 0, 0, 0);
    }

    const int colg = w * 16 + m;
    const float bv = bias[colg];

    float tl[16];
#pragma unroll
    for (int i = 0; i < 16; ++i) tl[i] = 0.f;

#pragma unroll
    for (int reg = 0; reg < 4; ++reg) {
        const int gr = nodeBase + quad * 4 + reg;          // always < NN (16|NN)
        const float v = fmaxf(acc[reg] + bv + skip[gr * 64 + colg], 0.f);
        if (out)  out[gr * 64 + colg]  = v;
        if (outb) outb[gr * 64 + colg] = f2bf(v);
        if (tOut) {
            const float4 uv = ((const float4*)uproj)[colg];
            tl[reg * 4 + 0] += v * uv.x;
            tl[reg * 4 + 1] += v * uv.y;
            tl[reg * 4 + 2] += v * uv.z;
            tl[reg * 4 + 3] += v * uv.w;
        }
    }

    if (tOut) {
        const float tv = multireduce16(tl, m);   // wave-partial over its 16 cols
        t_lds[w][lane] = tv;
        __syncthreads();
        if (w == 0) {
            const float tvf = t_lds[0][lane] + t_lds[1][lane] +
                              t_lds[2][lane] + t_lds[3][lane];
            tOut[nodeBase * 4 + lane] = tvf;     // row*4+h, contiguous 64 floats
        }
    }
}

extern "C" void kernel_launch(void* const* d_in, const int* in_sizes, int n_in,
                              void* d_out, int out_size, void* d_ws, size_t ws_size,
                              hipStream_t stream) {
    const float* x       = (const float*)d_in[0];
    const int*   ei      = (const int*)d_in[1];   // [2, NE] int32
    const float* lin1_w  = (const float*)d_in[2];
    const float* lin1_b  = (const float*)d_in[3];
    const float* lin2_w  = (const float*)d_in[4];
    const float* lin2_b  = (const float*)d_in[5];
    const float* lin3_w  = (const float*)d_in[6];
    const float* lin3_b  = (const float*)d_in[7];
    const float* conv1_w = (const float*)d_in[8];
    const float* conv1_u = (const float*)d_in[9];
    const float* conv1_c = (const float*)d_in[10];
    const float* conv1_bias = (const float*)d_in[11];
    const float* conv2_w = (const float*)d_in[12];
    const float* conv2_u = (const float*)d_in[13];
    const float* conv2_c = (const float*)d_in[14];
    const float* conv2_bias = (const float*)d_in[15];
    float* out = (float*)d_out;

    // workspace layout (16B-aligned sections)
    char* p = (char*)d_ws;
    float* skip   = (float*)p;           p += (size_t)NN * 64 * 4;
    float* tt     = (float*)p;           p += (size_t)NN * 4 * 4;   // t (layer 1)
    float* tt2    = (float*)p;           p += (size_t)NN * 4 * 4;   // t (layer 2)
    ushort16* ab  = (ushort16*)p;        p += (size_t)NN * 64 * 2;  // bf16 a
    ushort16* hb  = (ushort16*)p;        p += (size_t)NN * 64 * 2;  // bf16 h
    ushort16* pw12 = (ushort16*)p;       p += 16384 * 2;            // packed [W1|W2]
    ushort16* pwc1 = (ushort16*)p;       p += 16384 * 2;            // packed conv1_w
    ushort16* pwc2 = (ushort16*)p;       p += 16384 * 2;            // packed conv2_w
    ushort16* pwl3 = (ushort16*)p;       p += 4096 * 2;             // packed lin3_w
    int* ssrc     = (int*)p;             p += (size_t)NE * 4;
    int* row_ptr  = (int*)p;             p += (size_t)(NN + 1) * 4;
    int* bcnt     = (int*)p;             p += 256 * 4;              // bucket cursors
    uint32* pairs = (uint32*)p;          p += (size_t)NBUCK * BCAP * 4; // padded bins

    // ---- weight pre-pack + bcnt zero + CSR build (3 dispatches) ----
    k_packall<<<209, 256, 0, stream>>>(lin1_w, lin2_w, conv1_w, conv2_w, lin3_w,
                                       pw12, pwc1, pwc2, pwl3, bcnt);
    k_bin<<<(NE + EPB - 1) / EPB, 256, 0, stream>>>(ei, bcnt, pairs);
    k_binscat<<<NBUCK, 256, 0, stream>>>(pairs, bcnt, row_ptr, ssrc);

    // ---- layer 1 ----
    k_lin12<<<(NN + 63) / 64, 256, 0, stream>>>(x, pw12, lin1_b, lin2_b, conv1_u,
                                                ab, skip, tt);
    // fused agg+post: gathers ab/tt, writes h (bf16) + t2 (fp32, from fp32 v)
    k_aggpost<<<NN / 16, 256, 0, stream>>>(row_ptr, ssrc, tt, (const uint32*)ab,
                                           conv1_c, pwc1, conv1_bias, skip,
                                           nullptr, hb, conv2_u, tt2);

    // ---- layer 2 ----
    k_lin3m<<<(NN + 63) / 64, 256, 0, stream>>>(hb, pwl3, lin3_b, skip);
    k_aggpost<<<NN / 16, 256, 0, stream>>>(row_ptr, ssrc, tt2, (const uint32*)hb,
                                           conv2_c, pwc2, conv2_bias, skip,
                                           out, nullptr, nullptr, nullptr);
}

// Round 5
// 239.330 us; speedup vs baseline: 1.4094x; 1.0462x over previous
//
#include <hip/hip_runtime.h>

#define NN 50000
#define NE 800000
#define NBUCK ((NN + 255) / 256) // 196 dst-buckets of 256 nodes
#define EPB 4096                 // edges per k_bin block (16 per thread)
#define BCAP 8192                // padded per-bucket capacity (mean 4082, max~4.4k)

typedef unsigned int uint32;
typedef unsigned char uchar8;
typedef unsigned short ushort16;
typedef __attribute__((ext_vector_type(8))) short bf16x8;
typedef __attribute__((ext_vector_type(4))) float f32x4;

__device__ __forceinline__ ushort16 f2bf(float f) {
    uint32 u = __float_as_uint(f);
    u += 0x7fff + ((u >> 16) & 1);      // round-to-nearest-even
    return (ushort16)(u >> 16);
}
__device__ __forceinline__ float bf_lo(uint32 u) {
    return __uint_as_float(u << 16);
}
__device__ __forceinline__ float bf_hi(uint32 u) {
    return __uint_as_float(u & 0xffff0000u);
}
__device__ __forceinline__ bf16x8 pack8(const float4 a, const float4 b) {
    union { bf16x8 v; ushort16 u[8]; } r;
    r.u[0] = f2bf(a.x); r.u[1] = f2bf(a.y); r.u[2] = f2bf(a.z); r.u[3] = f2bf(a.w);
    r.u[4] = f2bf(b.x); r.u[5] = f2bf(b.y); r.u[6] = f2bf(b.z); r.u[7] = f2bf(b.w);
    return r.v;
}

// ---------------------------------------------------------------------------
// Butterfly multi-reduce: 16 values/lane over the 16 m-lanes of a quad.
// ---------------------------------------------------------------------------
__device__ __forceinline__ float multireduce16(const float* tl, int m) {
    float t8[8];
#pragma unroll
    for (int i = 0; i < 8; ++i) {
        const float a0 = tl[2 * i], b0 = tl[2 * i + 1];
        const float oa = __shfl_xor(a0, 1, 64), ob = __shfl_xor(b0, 1, 64);
        t8[i] = ((m & 1) == 0) ? (a0 + oa) : (b0 + ob);
    }
    float t4[4];
#pragma unroll
    for (int i = 0; i < 4; ++i) {
        const float a0 = t8[2 * i], b0 = t8[2 * i + 1];
        const float oa = __shfl_xor(a0, 2, 64), ob = __shfl_xor(b0, 2, 64);
        t4[i] = ((m & 2) == 0) ? (a0 + oa) : (b0 + ob);
    }
    float t2[2];
#pragma unroll
    for (int i = 0; i < 2; ++i) {
        const float a0 = t4[2 * i], b0 = t4[2 * i + 1];
        const float oa = __shfl_xor(a0, 4, 64), ob = __shfl_xor(b0, 4, 64);
        t2[i] = ((m & 4) == 0) ? (a0 + oa) : (b0 + ob);
    }
    const float a0 = t2[0], b0 = t2[1];
    const float oa = __shfl_xor(a0, 8, 64), ob = __shfl_xor(b0, 8, 64);
    return ((m & 8) == 0) ? (a0 + oa) : (b0 + ob);
}

// ---------------------------------------------------------------------------
// k_packall: all weight pre-packs fused + bcnt zero-init.
// ---------------------------------------------------------------------------
__device__ __forceinline__ ushort16 packp_val(const float* __restrict__ w, int i) {
    const int j  = i & 7;
    const int ln = (i >> 3) & 63;
    const int s  = (i >> 9) & 7;
    const int cc = i >> 12;
    const int k  = s * 32 + ((ln >> 4) * 8) + j;    // zcat idx (k-dim)
    const int n  = cc * 16 + (ln & 15);             // output col
    return f2bf(w[(k >> 2) * 256 + (k & 3) * 64 + n]);
}

__global__ __launch_bounds__(256) void k_packall(
    const float* __restrict__ w1, const float* __restrict__ w2,
    const float* __restrict__ wc1, const float* __restrict__ wc2,
    const float* __restrict__ wl3,
    ushort16* __restrict__ pw12, ushort16* __restrict__ pwc1,
    ushort16* __restrict__ pwc2, ushort16* __restrict__ pwl3,
    int* __restrict__ bcnt)
{
    const int gid = blockIdx.x * 256 + threadIdx.x;
    if (gid < 16384) {
        const int i = gid;
        const int j  = i & 7;
        const int ln = (i >> 3) & 63;
        const int s  = (i >> 9) & 3;
        const int cc = i >> 11;
        const int k  = s * 32 + ((ln >> 4) * 8) + j;    // 0..127
        const int n  = cc * 16 + (ln & 15);             // 0..127
        pw12[i] = f2bf((n < 64) ? w1[k * 64 + n] : w2[k * 64 + (n - 64)]);
    } else if (gid < 32768) {
        pwc1[gid - 16384] = packp_val(wc1, gid - 16384);
    } else if (gid < 49152) {
        pwc2[gid - 32768] = packp_val(wc2, gid - 32768);
    } else if (gid < 53248) {
        const int i = gid - 49152;                      // 0..4095
        const int j  = i & 7;
        const int ln = (i >> 3) & 63;
        const int s  = (i >> 9) & 1;
        const int cc = i >> 10;                         // 0..3
        const int k  = s * 32 + ((ln >> 4) * 8) + j;    // 0..63
        const int n  = cc * 16 + (ln & 15);             // 0..63
        pwl3[i] = f2bf(wl3[k * 64 + n]);
    } else if (gid < 53504) {
        bcnt[gid - 53248] = 0;
    }
}

// ---------------------------------------------------------------------------
// k_lin12 (MFMA): [a_bf16 | skip] = x @ [W1 | W2] + [b1 | b2], with the
// attention projection t = a @ u fused into the epilogue.
// ---------------------------------------------------------------------------
__global__ __launch_bounds__(256) void k_lin12(
    const float* __restrict__ x, const ushort16* __restrict__ pw,
    const float* __restrict__ b1, const float* __restrict__ b2,
    const float* __restrict__ u,
    ushort16* __restrict__ ab, float* __restrict__ skip,
    float* __restrict__ tOut)
{
    const int tid = threadIdx.x;
    const int lane = tid & 63;
    const int g = tid >> 6;
    const int m = lane & 15;
    const int quad = lane >> 4;
    const int rowBase = blockIdx.x * 64 + g * 16;

    const int arow = min(rowBase + m, NN - 1);
    const float* xr = x + (size_t)arow * 128 + quad * 8;

    f32x4 acc[8];
#pragma unroll
    for (int c = 0; c < 8; ++c)
#pragma unroll
        for (int r = 0; r < 4; ++r) acc[c][r] = 0.f;

#pragma unroll
    for (int s = 0; s < 4; ++s) {
        const float4 xa = *(const float4*)(xr + s * 32);
        const float4 xb = *(const float4*)(xr + s * 32 + 4);
        const bf16x8 af = pack8(xa, xb);
#pragma unroll
        for (int c = 0; c < 8; ++c) {
            const bf16x8 bf = *(const bf16x8*)&pw[((c * 4 + s) * 64 + lane) * 8];
            acc[c] = __builtin_amdgcn_mfma_f32_16x16x32_bf16(af, bf, acc[c], 0, 0, 0);
        }
    }

    float tl[16];
#pragma unroll
    for (int i = 0; i < 16; ++i) tl[i] = 0.f;

#pragma unroll
    for (int c = 0; c < 8; ++c) {
        const int colg = c * 16 + m;
        const float bv = (colg < 64) ? b1[colg] : b2[colg - 64];
#pragma unroll
        for (int reg = 0; reg < 4; ++reg) {
            const float v = acc[c][reg] + bv;
            const int gr = rowBase + quad * 4 + reg;
            if (gr < NN) {
                if (c < 4) ab[gr * 64 + colg] = f2bf(v);
                else       skip[gr * 64 + (colg - 64)] = v;
            }
            if (c < 4) {
                const float4 uv = ((const float4*)u)[colg];
                tl[reg * 4 + 0] += v * uv.x;
                tl[reg * 4 + 1] += v * uv.y;
                tl[reg * 4 + 2] += v * uv.z;
                tl[reg * 4 + 3] += v * uv.w;
            }
        }
    }

    const float tv = multireduce16(tl, m);
    const int gidx = rowBase * 4 + (quad << 4) + m;  // = row*4 + h, contiguous
    if (gidx < NN * 4) tOut[gidx] = tv;
}

// ---------------------------------------------------------------------------
// k_lin3m (MFMA): skip = h_bf16 @ W3 + b3  ([NN,64]@[64,64], K=64).
// ---------------------------------------------------------------------------
__global__ __launch_bounds__(256) void k_lin3m(
    const ushort16* __restrict__ hb, const ushort16* __restrict__ pw,
    const float* __restrict__ b, float* __restrict__ outp)
{
    const int tid = threadIdx.x;
    const int lane = tid & 63;
    const int g = tid >> 6;
    const int m = lane & 15;
    const int quad = lane >> 4;
    const int rowBase = blockIdx.x * 64 + g * 16;

    const int arow = min(rowBase + m, NN - 1);
    const ushort16* zrow = hb + (size_t)arow * 64 + quad * 8;

    f32x4 acc[4];
#pragma unroll
    for (int c = 0; c < 4; ++c)
#pragma unroll
        for (int r = 0; r < 4; ++r) acc[c][r] = 0.f;

#pragma unroll
    for (int s = 0; s < 2; ++s) {
        const bf16x8 af = *(const bf16x8*)(zrow + s * 32);
#pragma unroll
        for (int c = 0; c < 4; ++c) {
            const bf16x8 bf = *(const bf16x8*)&pw[((c * 2 + s) * 64 + lane) * 8];
            acc[c] = __builtin_amdgcn_mfma_f32_16x16x32_bf16(af, bf, acc[c], 0, 0, 0);
        }
    }

#pragma unroll
    for (int c = 0; c < 4; ++c) {
        const int colg = c * 16 + m;
        const float bv = b[colg];
#pragma unroll
        for (int reg = 0; reg < 4; ++reg) {
            const int gr = rowBase + quad * 4 + reg;
            if (gr < NN) outp[gr * 64 + colg] = acc[c][reg] + bv;
        }
    }
}

// ---------------------------------------------------------------------------
// CSR build: k_bin appends edges into bucket-PADDED `pairs`; k_binscat
// derives bucket bases + per-node row_ptr in-block and scatters ssrc + the
// 1-byte bucket-local dst (edst8) per edge.
// ---------------------------------------------------------------------------
__global__ __launch_bounds__(256) void k_bin(const int* __restrict__ ei,
                                             int* __restrict__ bcnt,
                                             uint32* __restrict__ pairs)
{
    __shared__ int hist[NBUCK];
    __shared__ int gbase[NBUCK];
    const int t = threadIdx.x;
    const int base = blockIdx.x * EPB;

    for (int b = t; b < NBUCK; b += 256) hist[b] = 0;
    __syncthreads();

    uint32 pk[16];
    int bk[16], rk[16];
#pragma unroll
    for (int k = 0; k < 16; ++k) {
        const int e = base + k * 256 + t;
        if (e < NE) {
            const int s = ei[e];
            const int d = ei[NE + e];
            bk[k] = d >> 8;
            pk[k] = (uint32)s | ((uint32)(d & 255) << 16);
            rk[k] = atomicAdd(&hist[bk[k]], 1);
        }
    }
    __syncthreads();

    for (int b = t; b < NBUCK; b += 256)
        gbase[b] = hist[b] ? atomicAdd(&bcnt[b], hist[b]) : 0;
    __syncthreads();

#pragma unroll
    for (int k = 0; k < 16; ++k) {
        const int e = base + k * 256 + t;
        if (e < NE) pairs[(size_t)bk[k] * BCAP + gbase[bk[k]] + rk[k]] = pk[k];
    }
}

__global__ __launch_bounds__(256) void k_binscat(const uint32* __restrict__ pairs,
                                                 const int* __restrict__ bcnt,
                                                 int* __restrict__ row_ptr,
                                                 int* __restrict__ ssrc,
                                                 uchar8* __restrict__ edst8)
{
    __shared__ int sb[256];
    __shared__ int hist[256];
    __shared__ int s[256];
    __shared__ int lptr[256];
    __shared__ int lcur[256];
    const int b = blockIdx.x;
    const int t = threadIdx.x;
    const int total = bcnt[b];
    const uint32* pb = pairs + (size_t)b * BCAP;

    // bucket-level exclusive base via block-local scan of all bucket counts
    sb[t] = (t < NBUCK) ? bcnt[t] : 0;
    __syncthreads();
    for (int off = 1; off < 256; off <<= 1) {
        const int v = (t >= off) ? sb[t - off] : 0;
        __syncthreads();
        sb[t] += v;
        __syncthreads();
    }
    const int base = sb[b] - total;
    if (b == 0 && t == 0) row_ptr[NN] = NE;

    hist[t] = 0;
    __syncthreads();
    for (int e = t; e < total; e += 256) atomicAdd(&hist[pb[e] >> 16], 1);
    __syncthreads();

    const int v = hist[t];
    s[t] = v;
    __syncthreads();
    for (int off = 1; off < 256; off <<= 1) {
        const int u = (t >= off) ? s[t - off] : 0;
        __syncthreads();
        s[t] += u;
        __syncthreads();
    }
    const int excl = base + s[t] - v;
    lptr[t] = excl;
    lcur[t] = 0;
    const int n = (b << 8) + t;
    if (n < NN) row_ptr[n] = excl;
    __syncthreads();

    for (int e = t; e < total; e += 256) {
        const uint32 p = pb[e];
        const int d = p >> 16;
        const int r = atomicAdd(&lcur[d], 1);
        const int pos = lptr[d] + r;
        ssrc[pos]  = (int)(p & 0xffffu);
        edst8[pos] = (uchar8)d;
    }
}

// ---------------------------------------------------------------------------
// k_aggpost: FUSED 3-phase aggregation + post-GEMM.
// Phase 0 (edge-parallel): block-stride over the block's contiguous CSR edge
//   range; each thread computes one edge's softmax q4 (identical formula to
//   the old per-lane path -> bit-identical) and writes fp32 qq[e] (same-XCD
//   L2, read back by phase 1).
// Phase 1: one wave per 4 sequential nodes; per edge-pair only 3 dependency-
//   free loads (ssrc seq / qq seq / abu gather) -- no shfl broadcasts, no
//   idle-lane softmax; 4 gathers in flight per unrolled body.
// Phase 2: 16x256 LDS tile -> MFMA post-GEMM + bias + skip + relu (+fused t).
// ---------------------------------------------------------------------------
__global__ __launch_bounds__(256) void k_aggpost(
    const int* __restrict__ row_ptr, const int* __restrict__ ssrc,
    const uchar8* __restrict__ edst8, float4* __restrict__ qq,
    const float* __restrict__ t, const uint32* __restrict__ abu,
    const float* __restrict__ c,
    const ushort16* __restrict__ pw, const float* __restrict__ bias,
    const float* __restrict__ skip,
    float* __restrict__ out, ushort16* __restrict__ outb,
    const float* __restrict__ uproj, float* __restrict__ tOut)
{
    __shared__ char zl[16 * 512];       // 16 nodes x 256 bf16, XOR-swizzled
    __shared__ float t_lds[4][64];

    const int tid = threadIdx.x;
    const int lane = tid & 63;
    const int w = tid >> 6;
    const int half = lane >> 5;
    const int u = lane & 31;
    const int nodeBase = blockIdx.x * 16;

    const float4 tc = *(const float4*)c;

    // ---- phase 0: per-edge softmax q -> qq (global, same-XCD L2) ----
    {
        const int r0b = row_ptr[nodeBase];
        const int r1b = row_ptr[nodeBase + 16];
        const int bucketBase = nodeBase & ~255;
        for (int i = r0b + tid; i < r1b; i += 256) {
            const int se = ssrc[i];
            const int dg = bucketBase + (int)edst8[i];
            const float4 ts = ((const float4*)t)[se];
            const float4 td = ((const float4*)t)[dg];
            const float invdeg = 1.f / (float)(row_ptr[dg + 1] - row_ptr[dg]);
            const float l0 = ts.x - td.x + tc.x;
            const float l1 = ts.y - td.y + tc.y;
            const float l2 = ts.z - td.z + tc.z;
            const float l3 = ts.w - td.w + tc.w;
            const float mx = fmaxf(fmaxf(l0, l1), fmaxf(l2, l3));
            const float e0 = __expf(l0 - mx);
            const float e1 = __expf(l1 - mx);
            const float e2 = __expf(l2 - mx);
            const float e3 = __expf(l3 - mx);
            const float sden = invdeg / (e0 + e1 + e2 + e3);
            qq[i] = make_float4(e0 * sden, e1 * sden, e2 * sden, e3 * sden);
        }
    }
    __syncthreads();

    // ---- phase 1: aggregation (4 sequential nodes per wave) ----
    for (int nn = 0; nn < 4; ++nn) {
        const int nloc = w * 4 + nn;
        const int node = nodeBase + nloc;

        const int r0 = row_ptr[node];
        const int r1 = row_ptr[node + 1];

        float z00 = 0.f, z01 = 0.f, z10 = 0.f, z11 = 0.f;
        float z20 = 0.f, z21 = 0.f, z30 = 0.f, z31 = 0.f;

        int idx = r0;
        for (; idx + 7 < r1; idx += 8) {
            const int se0 = ssrc[idx + half];
            const int se1 = ssrc[idx + 2 + half];
            const int se2 = ssrc[idx + 4 + half];
            const int se3 = ssrc[idx + 6 + half];
            const float4 qa = qq[idx + half];
            const float4 qb = qq[idx + 2 + half];
            const float4 qc = qq[idx + 4 + half];
            const float4 qd = qq[idx + 6 + half];
            const uint32 av0 = abu[se0 * 32 + u];
            const uint32 av1 = abu[se1 * 32 + u];
            const uint32 av2 = abu[se2 * 32 + u];
            const uint32 av3 = abu[se3 * 32 + u];
            {
                const float v0 = bf_lo(av0), v1 = bf_hi(av0);
                z00 += qa.x * v0; z01 += qa.x * v1;
                z10 += qa.y * v0; z11 += qa.y * v1;
                z20 += qa.z * v0; z21 += qa.z * v1;
                z30 += qa.w * v0; z31 += qa.w * v1;
            }
            {
                const float v0 = bf_lo(av1), v1 = bf_hi(av1);
                z00 += qb.x * v0; z01 += qb.x * v1;
                z10 += qb.y * v0; z11 += qb.y * v1;
                z20 += qb.z * v0; z21 += qb.z * v1;
                z30 += qb.w * v0; z31 += qb.w * v1;
            }
            {
                const float v0 = bf_lo(av2), v1 = bf_hi(av2);
                z00 += qc.x * v0; z01 += qc.x * v1;
                z10 += qc.y * v0; z11 += qc.y * v1;
                z20 += qc.z * v0; z21 += qc.z * v1;
                z30 += qc.w * v0; z31 += qc.w * v1;
            }
            {
                const float v0 = bf_lo(av3), v1 = bf_hi(av3);
                z00 += qd.x * v0; z01 += qd.x * v1;
                z10 += qd.y * v0; z11 += qd.y * v1;
                z20 += qd.z * v0; z21 += qd.z * v1;
                z30 += qd.w * v0; z31 += qd.w * v1;
            }
        }
        for (; idx + 1 < r1; idx += 2) {
            const int se = ssrc[idx + half];
            const float4 q4 = qq[idx + half];
            const uint32 av = abu[se * 32 + u];
            const float v0 = bf_lo(av), v1 = bf_hi(av);
            z00 += q4.x * v0; z01 += q4.x * v1;
            z10 += q4.y * v0; z11 += q4.y * v1;
            z20 += q4.z * v0; z21 += q4.z * v1;
            z30 += q4.w * v0; z31 += q4.w * v1;
        }
        if (idx < r1 && half == 0) {
            const int se = ssrc[idx];
            const float4 q4 = qq[idx];
            const uint32 av = abu[se * 32 + u];
            const float v0 = bf_lo(av), v1 = bf_hi(av);
            z00 += q4.x * v0; z01 += q4.x * v1;
            z10 += q4.y * v0; z11 += q4.y * v1;
            z20 += q4.z * v0; z21 += q4.z * v1;
            z30 += q4.w * v0; z31 += q4.w * v1;
        }

        z00 += __shfl_xor(z00, 32, 64); z01 += __shfl_xor(z01, 32, 64);
        z10 += __shfl_xor(z10, 32, 64); z11 += __shfl_xor(z11, 32, 64);
        z20 += __shfl_xor(z20, 32, 64); z21 += __shfl_xor(z21, 32, 64);
        z30 += __shfl_xor(z30, 32, 64); z31 += __shfl_xor(z31, 32, 64);

        if (half == 0) {
            uint4 pk;
            pk.x = (uint32)f2bf(z00) | ((uint32)f2bf(z10) << 16);
            pk.y = (uint32)f2bf(z20) | ((uint32)f2bf(z30) << 16);
            pk.z = (uint32)f2bf(z01) | ((uint32)f2bf(z11) << 16);
            pk.w = (uint32)f2bf(z21) | ((uint32)f2bf(z31) << 16);
            *(uint4*)(zl + nloc * 512 + ((u * 16) ^ ((nloc & 7) << 4))) = pk;
        }
    }
    __syncthreads();

    // ---- phase 2: post-GEMM from LDS (wave w -> cols w*16..+15) ----
    const int m = lane & 15;
    const int quad = lane >> 4;

    f32x4 acc;
#pragma unroll
    for (int r = 0; r < 4; ++r) acc[r] = 0.f;

#pragma unroll
    for (int s = 0; s < 8; ++s) {
        const bf16x8 af = *(const bf16x8*)(zl + m * 512 +
                            ((s * 64 + quad * 16) ^ ((m & 7) << 4)));
        const bf16x8 bf = *(const bf16x8*)&pw[((w * 8 + s) * 64 + lane) * 8];
        acc = __builtin_amdgcn_mfma_f32_16x16x32_bf16(af, bf, acc, 0, 0, 0);
    }

    const int colg = w * 16 + m;
    const float bv = bias[colg];

    float tl[16];
#pragma unroll
    for (int i = 0; i < 16; ++i) tl[i] = 0.f;

#pragma unroll
    for (int reg = 0; reg < 4; ++reg) {
        const int gr = nodeBase + quad * 4 + reg;          // always < NN (16|NN)
        const float v = fmaxf(acc[reg] + bv + skip[gr * 64 + colg], 0.f);
        if (out)  out[gr * 64 + colg]  = v;
        if (outb) outb[gr * 64 + colg] = f2bf(v);
        if (tOut) {
            const float4 uv = ((const float4*)uproj)[colg];
            tl[reg * 4 + 0] += v * uv.x;
            tl[reg * 4 + 1] += v * uv.y;
            tl[reg * 4 + 2] += v * uv.z;
            tl[reg * 4 + 3] += v * uv.w;
        }
    }

    if (tOut) {
        const float tv = multireduce16(tl, m);   // wave-partial over its 16 cols
        t_lds[w][lane] = tv;
        __syncthreads();
        if (w == 0) {
            const float tvf = t_lds[0][lane] + t_lds[1][lane] +
                              t_lds[2][lane] + t_lds[3][lane];
            tOut[nodeBase * 4 + lane] = tvf;     // row*4+h, contiguous 64 floats
        }
    }
}

extern "C" void kernel_launch(void* const* d_in, const int* in_sizes, int n_in,
                              void* d_out, int out_size, void* d_ws, size_t ws_size,
                              hipStream_t stream) {
    const float* x       = (const float*)d_in[0];
    const int*   ei      = (const int*)d_in[1];   // [2, NE] int32
    const float* lin1_w  = (const float*)d_in[2];
    const float* lin1_b  = (const float*)d_in[3];
    const float* lin2_w  = (const float*)d_in[4];
    const float* lin2_b  = (const float*)d_in[5];
    const float* lin3_w  = (const float*)d_in[6];
    const float* lin3_b  = (const float*)d_in[7];
    const float* conv1_w = (const float*)d_in[8];
    const float* conv1_u = (const float*)d_in[9];
    const float* conv1_c = (const float*)d_in[10];
    const float* conv1_bias = (const float*)d_in[11];
    const float* conv2_w = (const float*)d_in[12];
    const float* conv2_u = (const float*)d_in[13];
    const float* conv2_c = (const float*)d_in[14];
    const float* conv2_bias = (const float*)d_in[15];
    float* out = (float*)d_out;

    // workspace layout (16B-aligned sections)
    char* p = (char*)d_ws;
    float* skip   = (float*)p;           p += (size_t)NN * 64 * 4;
    float* tt     = (float*)p;           p += (size_t)NN * 4 * 4;   // t (layer 1)
    float* tt2    = (float*)p;           p += (size_t)NN * 4 * 4;   // t (layer 2)
    ushort16* ab  = (ushort16*)p;        p += (size_t)NN * 64 * 2;  // bf16 a
    ushort16* hb  = (ushort16*)p;        p += (size_t)NN * 64 * 2;  // bf16 h
    ushort16* pw12 = (ushort16*)p;       p += 16384 * 2;            // packed [W1|W2]
    ushort16* pwc1 = (ushort16*)p;       p += 16384 * 2;            // packed conv1_w
    ushort16* pwc2 = (ushort16*)p;       p += 16384 * 2;            // packed conv2_w
    ushort16* pwl3 = (ushort16*)p;       p += 4096 * 2;             // packed lin3_w
    int* ssrc     = (int*)p;             p += (size_t)NE * 4;
    int* row_ptr  = (int*)p;             p += (size_t)(NN + 1) * 4;
    int* bcnt     = (int*)p;             p += 256 * 4;              // bucket cursors
    uchar8* edst8 = (uchar8*)p;          p += (size_t)NE;           // bucket-local dst
    p = (char*)(((size_t)p + 15) & ~(size_t)15);
    float4* qq    = (float4*)p;          p += (size_t)NE * 16;      // per-edge q
    uint32* pairs = (uint32*)p;          p += (size_t)NBUCK * BCAP * 4; // padded bins

    // ---- weight pre-pack + bcnt zero + CSR build (3 dispatches) ----
    k_packall<<<209, 256, 0, stream>>>(lin1_w, lin2_w, conv1_w, conv2_w, lin3_w,
                                       pw12, pwc1, pwc2, pwl3, bcnt);
    k_bin<<<(NE + EPB - 1) / EPB, 256, 0, stream>>>(ei, bcnt, pairs);
    k_binscat<<<NBUCK, 256, 0, stream>>>(pairs, bcnt, row_ptr, ssrc, edst8);

    // ---- layer 1 ----
    k_lin12<<<(NN + 63) / 64, 256, 0, stream>>>(x, pw12, lin1_b, lin2_b, conv1_u,
                                                ab, skip, tt);
    k_aggpost<<<NN / 16, 256, 0, stream>>>(row_ptr, ssrc, edst8, qq, tt,
                                           (const uint32*)ab, conv1_c,
                                           pwc1, conv1_bias, skip,
                                           nullptr, hb, conv2_u, tt2);

    // ---- layer 2 ----
    k_lin3m<<<(NN + 63) / 64, 256, 0, stream>>>(hb, pwl3, lin3_b, skip);
    k_aggpost<<<NN / 16, 256, 0, stream>>>(row_ptr, ssrc, edst8, qq, tt2,
                                           (const uint32*)hb, conv2_c,
                                           pwc2, conv2_bias, skip,
                                           out, nullptr, nullptr, nullptr);
}